// Round 2
// baseline (910.807 us; speedup 1.0000x reference)
//
#include <hip/hip_runtime.h>
#include <hip/hip_bf16.h>

#define DIMX 1024
#define DSTATE 16
#define DCONV 4
#define DINNER 2048
#define DTRANK 64
#define BSZ 2
#define SEQL 1024
#define NROW (BSZ*SEQL)              // 2048
#define NPROJ (DTRANK + 2*DSTATE)    // 96

__device__ __forceinline__ float sigmoidf_(float x){ return 1.0f/(1.0f+__expf(-x)); }

// ---------------------------------------------------------------------------
// Tiled f32 GEMM: C(MxN) = A(MxK) @ B(KxN) [+ bias, softplus if EPI==1]
// 64x64 tile, BK=16, 256 threads, 4x4 micro-tile per thread.
// Requires: K % 16 == 0, M % 64 == 0 (true for all uses). N arbitrary (mult of 4).
// ---------------------------------------------------------------------------
template<int EPI>
__global__ __launch_bounds__(256) void gemm_k(
    const float* __restrict__ Ap, int lda,
    const float* __restrict__ Bp, int ldb,
    float* __restrict__ Cp, int ldc,
    int M, int N, int K,
    const float* __restrict__ bias)
{
  __shared__ float As[16][64];
  __shared__ float Bs[16][64];
  const int tid = threadIdx.x;
  const int tx = tid & 15, ty = tid >> 4;
  const int rowTile = blockIdx.y * 64;
  const int colTile = blockIdx.x * 64;

  const int ar = tid >> 2;          // 0..63  (A tile row)
  const int ak = (tid & 3) * 4;     // 0,4,8,12 (A tile k)
  const int bk = tid >> 4;          // 0..15  (B tile k)
  const int bn = (tid & 15) * 4;    // 0..60  (B tile col)

  float acc[4][4] = {};

  for (int k0 = 0; k0 < K; k0 += 16) {
    // ---- stage A tile (rows always valid: M % 64 == 0; k always valid) ----
    {
      const int r = rowTile + ar;
      float4 av = *(const float4*)(Ap + (size_t)r * lda + k0 + ak);
      As[ak+0][ar] = av.x; As[ak+1][ar] = av.y;
      As[ak+2][ar] = av.z; As[ak+3][ar] = av.w;
    }
    // ---- stage B tile ----
    {
      const int kk = k0 + bk;
      const int c = colTile + bn;
      float4 bv;
      if (c + 3 < N) {
        bv = *(const float4*)(Bp + (size_t)kk * ldb + c);
      } else {
        bv.x = (c+0 < N) ? Bp[(size_t)kk*ldb + c+0] : 0.f;
        bv.y = (c+1 < N) ? Bp[(size_t)kk*ldb + c+1] : 0.f;
        bv.z = (c+2 < N) ? Bp[(size_t)kk*ldb + c+2] : 0.f;
        bv.w = (c+3 < N) ? Bp[(size_t)kk*ldb + c+3] : 0.f;
      }
      *(float4*)&Bs[bk][bn] = bv;
    }
    __syncthreads();
    #pragma unroll
    for (int kk = 0; kk < 16; kk++) {
      float4 a4 = *(const float4*)&As[kk][ty*4];
      float4 b4 = *(const float4*)&Bs[kk][tx*4];
      float a[4] = {a4.x, a4.y, a4.z, a4.w};
      float b[4] = {b4.x, b4.y, b4.z, b4.w};
      #pragma unroll
      for (int i = 0; i < 4; i++)
        #pragma unroll
        for (int j = 0; j < 4; j++)
          acc[i][j] += a[i] * b[j];
    }
    __syncthreads();
  }

  #pragma unroll
  for (int i = 0; i < 4; i++) {
    const int r = rowTile + ty*4 + i;
    #pragma unroll
    for (int j = 0; j < 4; j++) {
      const int c = colTile + tx*4 + j;
      if (c >= N) continue;
      float v = acc[i][j];
      if constexpr (EPI == 1) {      // softplus(v + bias)
        v += bias[c];
        v = (v > 20.f) ? v : log1pf(__expf(v));
      }
      Cp[(size_t)r*ldc + c] = v;
    }
  }
}

// ---------------------------------------------------------------------------
// Causal depthwise conv (width 4) + SiLU: u[b,l,d] = silu(b[d] + sum_k xc[b,l-3+k,d]*w[d,k])
// xc lives in xz buffer (row stride 4096, cols 0..2047).
// ---------------------------------------------------------------------------
__global__ __launch_bounds__(256) void conv_silu_k(
    const float* __restrict__ xz,
    const float* __restrict__ conv_w,
    const float* __restrict__ conv_b,
    float* __restrict__ u)
{
  const int idx = blockIdx.x * 256 + threadIdx.x;   // over NROW*DINNER
  if (idx >= NROW * DINNER) return;
  const int d = idx & (DINNER - 1);
  const int row = idx >> 11;            // b*SEQL + l
  const int l = row & (SEQL - 1);
  float acc = conv_b[d];
  #pragma unroll
  for (int k = 0; k < DCONV; k++) {
    const int ls = l + k - (DCONV - 1);
    if (ls >= 0)
      acc += xz[(size_t)(row + k - (DCONV - 1)) * 4096 + d] * conv_w[d*DCONV + k];
  }
  u[idx] = acc * sigmoidf_(acc);
}

// ---------------------------------------------------------------------------
// Selective scan. Block = 256 threads = 16 channels x 16 states.
// Grid = BSZ * (DINNER/16) = 256 blocks. Chunked LDS staging (64 timesteps).
// Writes y = (scan_y + u*D)*silu(z) into xz cols 0..2047 (xc region, dead).
// ---------------------------------------------------------------------------
__global__ __launch_bounds__(256) void scan_k(
    const float* __restrict__ delta,
    const float* __restrict__ u,
    float* __restrict__ xz,               // z source (cols 2048..4095) and y dest (cols 0..2047)
    const float* __restrict__ x_dbl,
    const float* __restrict__ A_log,
    const float* __restrict__ Dp)
{
  const int b = blockIdx.x >> 7;            // 128 blocks per batch
  const int dBase = (blockIdx.x & 127) * 16;
  const int tid = threadIdx.x;
  const int g = tid >> 4;                   // channel within block (0..15)
  const int n = tid & 15;                   // state (0..15)
  const int d = dBase + g;

  const float Aval = -__expf(A_log[d*DSTATE + n]);
  const float Dval = Dp[d];

  __shared__ float delta_s[64][16], u_s[64][16], z_s[64][16];
  __shared__ float Bm_s[64][16], Cm_s[64][16], y_s[64][16];

  const int t4 = tid >> 2;                  // 0..63 (loader row)
  const int j4 = (tid & 3) * 4;             // 0,4,8,12 (loader col)

  float h = 0.f;

  for (int t0 = 0; t0 < SEQL; t0 += 64) {
    const size_t rowL = (size_t)(b*SEQL + t0 + t4);
    *(float4*)&delta_s[t4][j4] = *(const float4*)&delta[rowL*DINNER + dBase + j4];
    *(float4*)&u_s[t4][j4]     = *(const float4*)&u[rowL*DINNER + dBase + j4];
    *(float4*)&z_s[t4][j4]     = *(const float4*)&xz[rowL*4096 + DINNER + dBase + j4];
    *(float4*)&Bm_s[t4][j4]    = *(const float4*)&x_dbl[rowL*NPROJ + DTRANK + j4];
    *(float4*)&Cm_s[t4][j4]    = *(const float4*)&x_dbl[rowL*NPROJ + DTRANK + DSTATE + j4];
    __syncthreads();

    for (int t = 0; t < 64; t++) {
      const float dlt = delta_s[t][g];
      const float uu  = u_s[t][g];
      const float dA  = __expf(dlt * Aval);
      h = dA * h + (dlt * uu) * Bm_s[t][n];
      float p = h * Cm_s[t][n];
      p += __shfl_xor(p, 8);
      p += __shfl_xor(p, 4);
      p += __shfl_xor(p, 2);
      p += __shfl_xor(p, 1);
      if (n == 0) {
        const float zv = z_s[t][g];
        y_s[t][g] = (p + uu * Dval) * (zv * sigmoidf_(zv));
      }
    }
    __syncthreads();
    *(float4*)&xz[rowL*4096 + dBase + j4] = *(const float4*)&y_s[t4][j4];
  }
}

// ---------------------------------------------------------------------------
extern "C" void kernel_launch(void* const* d_in, const int* in_sizes, int n_in,
                              void* d_out, int out_size, void* d_ws, size_t ws_size,
                              hipStream_t stream) {
  // inputs (f32 per reference dtypes): 0 x, 1 mask(bool all-true -> ignored),
  // 2 in_proj_w, 3 conv_w, 4 conv_b, 5 x_proj_w, 6 dt_proj_w, 7 dt_proj_b,
  // 8 A_log, 9 D, 10 out_proj_w
  const float* x         = (const float*)d_in[0];
  const float* in_proj_w = (const float*)d_in[2];
  const float* conv_w    = (const float*)d_in[3];
  const float* conv_b    = (const float*)d_in[4];
  const float* x_proj_w  = (const float*)d_in[5];
  const float* dt_proj_w = (const float*)d_in[6];
  const float* dt_proj_b = (const float*)d_in[7];
  const float* A_log     = (const float*)d_in[8];
  const float* Dp        = (const float*)d_in[9];
  const float* out_proj_w= (const float*)d_in[10];
  float* out = (float*)d_out;

  // workspace layout (f32): xz[NROW][4096] | u[NROW][2048] | x_dbl[NROW][96] | delta[NROW][2048]
  // total ~64.8 MB; y re-uses xz cols 0..2047 (xc region, dead after conv)
  float* xz    = (float*)d_ws;
  float* u     = xz + (size_t)NROW * 4096;
  float* xdbl  = u  + (size_t)NROW * DINNER;
  float* delta = xdbl + (size_t)NROW * NPROJ;

  dim3 blk(256);

  // GEMM1: xz = x @ in_proj_w   (2048 x 4096 x 1024)
  gemm_k<0><<<dim3(4096/64, NROW/64), blk, 0, stream>>>(
      x, DIMX, in_proj_w, 2*DINNER, xz, 2*DINNER, NROW, 2*DINNER, DIMX, nullptr);

  // conv + silu -> u
  conv_silu_k<<<(NROW*DINNER)/256, blk, 0, stream>>>(xz, conv_w, conv_b, u);

  // GEMM2: x_dbl = u @ x_proj_w (2048 x 96 x 2048)
  gemm_k<0><<<dim3((NPROJ+63)/64, NROW/64), blk, 0, stream>>>(
      u, DINNER, x_proj_w, NPROJ, xdbl, NPROJ, NROW, NPROJ, DINNER, nullptr);

  // GEMM3: delta = softplus(dtr @ dt_proj_w + dt_proj_b) (2048 x 2048 x 64)
  gemm_k<1><<<dim3(DINNER/64, NROW/64), blk, 0, stream>>>(
      xdbl, NPROJ, dt_proj_w, DINNER, delta, DINNER, NROW, DINNER, DTRANK, dt_proj_b);

  // selective scan + epilogue -> y (aliased into xz cols 0..2047)
  scan_k<<<dim3(BSZ * (DINNER/16)), blk, 0, stream>>>(delta, u, xz, xdbl, A_log, Dp);

  // GEMM4: out = y @ out_proj_w (2048 x 1024 x 2048)
  gemm_k<0><<<dim3(DIMX/64, NROW/64), blk, 0, stream>>>(
      xz, 4096, out_proj_w, DIMX, out, DIMX, NROW, DIMX, DINNER, nullptr);
}

// Round 4
// 461.570 us; speedup vs baseline: 1.9733x; 1.9733x over previous
//
#include <hip/hip_runtime.h>
#include <hip/hip_bf16.h>

#define DIMX 1024
#define DSTATE 16
#define DCONV 4
#define DINNER 2048
#define DTRANK 64
#define BSZ 2
#define SEQL 1024
#define NROW (BSZ*SEQL)              // 2048
#define NPROJ (DTRANK + 2*DSTATE)    // 96
#define NCHUNK 16
#define CLEN 64                      // SEQL / NCHUNK

typedef __bf16 bf16x8 __attribute__((ext_vector_type(8)));
typedef float f32x4 __attribute__((ext_vector_type(4)));
typedef unsigned short ushort8_t __attribute__((ext_vector_type(8)));

__device__ __forceinline__ float sigmoidf_(float x){ return 1.0f/(1.0f+__expf(-x)); }
__device__ __forceinline__ unsigned short f2bf(float f){
  union { float f; unsigned int i; } c; c.f = f;
  unsigned int r = (c.i + 0x7FFFu + ((c.i >> 16) & 1u)) >> 16;
  return (unsigned short)r;
}
__device__ __forceinline__ float bf2f(unsigned short u){
  union { unsigned int i; float f; } c; c.i = ((unsigned int)u) << 16; return c.f;
}

// ---------------------------------------------------------------------------
// Transpose + cast: w (K x N, f32) -> wt (N x K, bf16). Grid (N/32, K/32).
// ---------------------------------------------------------------------------
__global__ __launch_bounds__(256) void transpose_cast_k(
    const float* __restrict__ w, unsigned short* __restrict__ wt, int K, int N)
{
  __shared__ unsigned short T[32][33];
  const int nT = blockIdx.x * 32, kT = blockIdx.y * 32;
  const int tx = threadIdx.x & 31, ty = threadIdx.x >> 5;   // ty 0..7
  #pragma unroll
  for (int i = 0; i < 4; i++) {
    const int k = kT + ty + i*8;
    T[tx][ty + i*8] = f2bf(w[(size_t)k * N + nT + tx]);
  }
  __syncthreads();
  #pragma unroll
  for (int i = 0; i < 4; i++) {
    const int n = nT + ty + i*8;
    wt[(size_t)n * K + kT + tx] = T[ty + i*8][tx];
  }
}

// ---------------------------------------------------------------------------
// MFMA GEMM: C = A(f32, cast->bf16 in staging) @ BT^T;  BT (N x K) bf16.
// BM=128, BK=32, BN in {128,64}. 256 thr = 4 waves. LDS row stride 40 bf16.
// C-write splits at column splitN: col<splitN -> C0[row*ldc+col],
// else C1[row*ldc+col-splitN]. (For a single output pass splitN >= N.)
// ---------------------------------------------------------------------------
template<int BN>
__global__ __launch_bounds__(256) void gemm_mfma_k(
    const float* __restrict__ A, int lda,
    const unsigned short* __restrict__ BT, int ldb,
    float* __restrict__ C0, float* __restrict__ C1, int splitN, int ldc,
    int K)
{
  constexpr int BM = 128;
  constexpr int WCOLS = BN / 64;
  constexpr int WROWS = 4 / WCOLS;
  constexpr int WM = BM / WROWS;
  constexpr int MI = WM / 16;
  constexpr int NI = 4;

  __shared__ unsigned short As[BM * 40];
  __shared__ unsigned short Bs[BN * 40];

  const int tid = threadIdx.x;
  const int w = tid >> 6, lane = tid & 63;
  const int quad = lane >> 4, lrow = lane & 15;
  const int waveM = w % WROWS, waveN = w / WROWS;
  const int mOff = waveM * WM, nOff = waveN * 64;
  const int rowTile = blockIdx.y * BM, colTile = blockIdx.x * BN;

  f32x4 acc[MI][NI] = {};

  const int sr = tid >> 2;          // 0..63
  const int sc = (tid & 3) * 8;     // 0,8,16,24

  for (int k0 = 0; k0 < K; k0 += 32) {
    #pragma unroll
    for (int i = 0; i < BM/64; i++) {
      const int r = sr + i*64;
      const float* src = A + (size_t)(rowTile + r) * lda + k0 + sc;
      float4 v0 = *(const float4*)src;
      float4 v1 = *(const float4*)(src + 4);
      ushort8_t t;
      t[0]=f2bf(v0.x); t[1]=f2bf(v0.y); t[2]=f2bf(v0.z); t[3]=f2bf(v0.w);
      t[4]=f2bf(v1.x); t[5]=f2bf(v1.y); t[6]=f2bf(v1.z); t[7]=f2bf(v1.w);
      *(ushort8_t*)&As[r*40 + sc] = t;
    }
    #pragma unroll
    for (int i = 0; i < BN/64; i++) {
      const int r = sr + i*64;
      *(ushort8_t*)&Bs[r*40 + sc] =
          *(const ushort8_t*)(BT + (size_t)(colTile + r) * ldb + k0 + sc);
    }
    __syncthreads();

    bf16x8 af[MI], bfr[NI];
    #pragma unroll
    for (int mi = 0; mi < MI; mi++)
      af[mi] = *(const bf16x8*)&As[(mOff + mi*16 + lrow)*40 + quad*8];
    #pragma unroll
    for (int ni = 0; ni < NI; ni++)
      bfr[ni] = *(const bf16x8*)&Bs[(nOff + ni*16 + lrow)*40 + quad*8];
    #pragma unroll
    for (int mi = 0; mi < MI; mi++)
      #pragma unroll
      for (int ni = 0; ni < NI; ni++)
        acc[mi][ni] = __builtin_amdgcn_mfma_f32_16x16x32_bf16(
            af[mi], bfr[ni], acc[mi][ni], 0, 0, 0);
    __syncthreads();
  }

  #pragma unroll
  for (int mi = 0; mi < MI; mi++) {
    #pragma unroll
    for (int ni = 0; ni < NI; ni++) {
      const int row = rowTile + mOff + mi*16 + quad*4;
      const int col = colTile + nOff + ni*16 + lrow;
      float* Cb = (col < splitN) ? C0 : C1;
      const int cc = (col < splitN) ? col : col - splitN;
      #pragma unroll
      for (int r = 0; r < 4; r++)
        Cb[(size_t)(row + r) * ldc + cc] = acc[mi][ni][r];
    }
  }
}

// ---------------------------------------------------------------------------
// Tiled f32 GEMM (GEMM2/GEMM3). OUT_BF16: store bf16. EPI==1: softplus+bias.
// ---------------------------------------------------------------------------
template<int EPI, int OUT_BF16>
__global__ __launch_bounds__(256) void gemm_k(
    const float* __restrict__ Ap, int lda,
    const float* __restrict__ Bp, int ldb,
    void* __restrict__ Cp, int ldc,
    int M, int N, int K,
    const float* __restrict__ bias)
{
  __shared__ float As[16][64];
  __shared__ float Bs[16][64];
  const int tid = threadIdx.x;
  const int tx = tid & 15, ty = tid >> 4;
  const int rowTile = blockIdx.y * 64;
  const int colTile = blockIdx.x * 64;

  const int ar = tid >> 2;
  const int ak = (tid & 3) * 4;
  const int bk = tid >> 4;
  const int bn = (tid & 15) * 4;

  float acc[4][4] = {};

  for (int k0 = 0; k0 < K; k0 += 16) {
    {
      const int r = rowTile + ar;
      float4 av = *(const float4*)(Ap + (size_t)r * lda + k0 + ak);
      As[ak+0][ar] = av.x; As[ak+1][ar] = av.y;
      As[ak+2][ar] = av.z; As[ak+3][ar] = av.w;
    }
    {
      const int kk = k0 + bk;
      const int c = colTile + bn;
      float4 bv;
      if (c + 3 < N) {
        bv = *(const float4*)(Bp + (size_t)kk * ldb + c);
      } else {
        bv.x = (c+0 < N) ? Bp[(size_t)kk*ldb + c+0] : 0.f;
        bv.y = (c+1 < N) ? Bp[(size_t)kk*ldb + c+1] : 0.f;
        bv.z = (c+2 < N) ? Bp[(size_t)kk*ldb + c+2] : 0.f;
        bv.w = (c+3 < N) ? Bp[(size_t)kk*ldb + c+3] : 0.f;
      }
      *(float4*)&Bs[bk][bn] = bv;
    }
    __syncthreads();
    #pragma unroll
    for (int kk = 0; kk < 16; kk++) {
      float4 a4 = *(const float4*)&As[kk][ty*4];
      float4 b4 = *(const float4*)&Bs[kk][tx*4];
      float a[4] = {a4.x, a4.y, a4.z, a4.w};
      float b[4] = {b4.x, b4.y, b4.z, b4.w};
      #pragma unroll
      for (int i = 0; i < 4; i++)
        #pragma unroll
        for (int j = 0; j < 4; j++)
          acc[i][j] += a[i] * b[j];
    }
    __syncthreads();
  }

  #pragma unroll
  for (int i = 0; i < 4; i++) {
    const int r = rowTile + ty*4 + i;
    #pragma unroll
    for (int j = 0; j < 4; j++) {
      const int c = colTile + tx*4 + j;
      if (c >= N) continue;
      float v = acc[i][j];
      if constexpr (EPI == 1) {
        v += bias[c];
        v = (v > 20.f) ? v : log1pf(__expf(v));
      }
      if constexpr (OUT_BF16) ((unsigned short*)Cp)[(size_t)r*ldc + c] = f2bf(v);
      else                    ((float*)Cp)[(size_t)r*ldc + c] = v;
    }
  }
}

// ---------------------------------------------------------------------------
// Causal depthwise conv (width 4) + SiLU. xc: (NROW x 2048 f32, contiguous).
// ---------------------------------------------------------------------------
__global__ __launch_bounds__(256) void conv_silu_k(
    const float* __restrict__ xc,
    const float* __restrict__ conv_w,
    const float* __restrict__ conv_b,
    float* __restrict__ u)
{
  const int idx = blockIdx.x * 256 + threadIdx.x;
  if (idx >= NROW * DINNER) return;
  const int d = idx & (DINNER - 1);
  const int row = idx >> 11;
  const int l = row & (SEQL - 1);
  float acc = conv_b[d];
  #pragma unroll
  for (int k = 0; k < DCONV; k++) {
    const int ls = l + k - (DCONV - 1);
    if (ls >= 0)
      acc += xc[(size_t)(row + k - (DCONV - 1)) * DINNER + d] * conv_w[d*DCONV + k];
  }
  u[idx] = acc * sigmoidf_(acc);
}

// ---------------------------------------------------------------------------
// Chunked parallel scan. h_t = a_t h_{t-1} + b_t,  a_t = exp(delta_t*A),
// b_t = delta_t*u_t*B_t.  L=1024 -> 16 chunks of 64.
// Block = 256 thr = 16 channels x 16 states; grid (b, dgroup, chunk).
// Phase1: local scan from 0 -> S[b][c][d][n]; decay P = exp(A*sum delta).
// Phase2: serial over 16 chunks per (b,d,n): H[c] = chunk-start state.
// Phase3: re-run chunk seeded with H, reduce over n, fused epilogue -> y.
// ---------------------------------------------------------------------------
__global__ __launch_bounds__(256) void scan_p1(
    const unsigned short* __restrict__ delta16,
    const float* __restrict__ u,
    const float* __restrict__ xdbl,
    const float* __restrict__ A_log,
    float* __restrict__ S, float* __restrict__ P)
{
  const int c = blockIdx.x & 15;
  const int dg = (blockIdx.x >> 4) & 127;
  const int b = blockIdx.x >> 11;
  const int dBase = dg * 16;
  const int tid = threadIdx.x;
  const int g = tid >> 4, n = tid & 15;
  const int d = dBase + g;
  const float Aval = -__expf(A_log[d*DSTATE + n]);

  __shared__ float delta_s[CLEN][16], u_s[CLEN][16], Bm_s[CLEN][16];
  const int t4 = tid >> 2, j4 = (tid & 3) * 4;
  const size_t rowL = (size_t)(b*SEQL + c*CLEN + t4);
  {
    ushort4 dv = *(const ushort4*)&delta16[rowL*DINNER + dBase + j4];
    delta_s[t4][j4+0] = bf2f(dv.x); delta_s[t4][j4+1] = bf2f(dv.y);
    delta_s[t4][j4+2] = bf2f(dv.z); delta_s[t4][j4+3] = bf2f(dv.w);
  }
  *(float4*)&u_s[t4][j4]  = *(const float4*)&u[rowL*DINNER + dBase + j4];
  *(float4*)&Bm_s[t4][j4] = *(const float4*)&xdbl[rowL*NPROJ + DTRANK + j4];
  __syncthreads();

  float h = 0.f, sumd = 0.f;
  #pragma unroll 4
  for (int t = 0; t < CLEN; t++) {
    const float dlt = delta_s[t][g];
    const float a = __expf(dlt * Aval);
    h = a * h + (dlt * u_s[t][g]) * Bm_s[t][n];
    sumd += dlt;
  }
  const size_t idx = ((size_t)(b*NCHUNK + c) * DINNER + d) * DSTATE + n;
  S[idx] = h;
  P[idx] = __expf(Aval * sumd);
}

__global__ __launch_bounds__(256) void scan_p2(
    const float* __restrict__ S, const float* __restrict__ P,
    float* __restrict__ H)
{
  const int idx = blockIdx.x * 256 + threadIdx.x;   // (b,d,n): 65536
  const int n = idx & 15, d = (idx >> 4) & (DINNER-1), b = idx >> 15;
  float h = 0.f;
  #pragma unroll
  for (int c = 0; c < NCHUNK; c++) {
    const size_t base = ((size_t)(b*NCHUNK + c) * DINNER + d) * DSTATE + n;
    H[base] = h;                       // chunk-start state
    h = P[base] * h + S[base];
  }
}

__global__ __launch_bounds__(256) void scan_p3(
    const unsigned short* __restrict__ delta16,
    const float* __restrict__ u,
    const float* __restrict__ Z,
    const float* __restrict__ xdbl,
    const float* __restrict__ A_log,
    const float* __restrict__ Dp,
    const float* __restrict__ H,
    float* __restrict__ Y)
{
  const int c = blockIdx.x & 15;
  const int dg = (blockIdx.x >> 4) & 127;
  const int b = blockIdx.x >> 11;
  const int dBase = dg * 16;
  const int tid = threadIdx.x;
  const int g = tid >> 4, n = tid & 15;
  const int d = dBase + g;
  const float Aval = -__expf(A_log[d*DSTATE + n]);
  const float Dval = Dp[d];

  __shared__ float delta_s[CLEN][16], u_s[CLEN][16], z_s[CLEN][16];
  __shared__ float Bm_s[CLEN][16], Cm_s[CLEN][16], y_s[CLEN][16];
  const int t4 = tid >> 2, j4 = (tid & 3) * 4;
  const size_t rowL = (size_t)(b*SEQL + c*CLEN + t4);
  {
    ushort4 dv = *(const ushort4*)&delta16[rowL*DINNER + dBase + j4];
    delta_s[t4][j4+0] = bf2f(dv.x); delta_s[t4][j4+1] = bf2f(dv.y);
    delta_s[t4][j4+2] = bf2f(dv.z); delta_s[t4][j4+3] = bf2f(dv.w);
  }
  *(float4*)&u_s[t4][j4]  = *(const float4*)&u[rowL*DINNER + dBase + j4];
  *(float4*)&z_s[t4][j4]  = *(const float4*)&Z[rowL*DINNER + dBase + j4];
  *(float4*)&Bm_s[t4][j4] = *(const float4*)&xdbl[rowL*NPROJ + DTRANK + j4];
  *(float4*)&Cm_s[t4][j4] = *(const float4*)&xdbl[rowL*NPROJ + DTRANK + DSTATE + j4];
  __syncthreads();

  float h = H[((size_t)(b*NCHUNK + c) * DINNER + d) * DSTATE + n];
  for (int t = 0; t < CLEN; t++) {
    const float dlt = delta_s[t][g];
    const float uu  = u_s[t][g];
    const float a = __expf(dlt * Aval);
    h = a * h + (dlt * uu) * Bm_s[t][n];
    float p = h * Cm_s[t][n];
    p += __shfl_xor(p, 8);
    p += __shfl_xor(p, 4);
    p += __shfl_xor(p, 2);
    p += __shfl_xor(p, 1);
    if (n == 0) {
      const float zv = z_s[t][g];
      y_s[t][g] = (p + uu * Dval) * (zv * sigmoidf_(zv));
    }
  }
  __syncthreads();
  *(float4*)&Y[rowL*DINNER + dBase + j4] = *(const float4*)&y_s[t4][j4];
}

// ---------------------------------------------------------------------------
extern "C" void kernel_launch(void* const* d_in, const int* in_sizes, int n_in,
                              void* d_out, int out_size, void* d_ws, size_t ws_size,
                              hipStream_t stream) {
  const float* x         = (const float*)d_in[0];
  const float* in_proj_w = (const float*)d_in[2];
  const float* conv_w    = (const float*)d_in[3];
  const float* conv_b    = (const float*)d_in[4];
  const float* x_proj_w  = (const float*)d_in[5];
  const float* dt_proj_w = (const float*)d_in[6];
  const float* dt_proj_b = (const float*)d_in[7];
  const float* A_log     = (const float*)d_in[8];
  const float* Dp        = (const float*)d_in[9];
  const float* out_proj_w= (const float*)d_in[10];
  float* out = (float*)d_out;

  // ws layout — EXACTLY the R2-proven 67,895,296 bytes. Aliasing timeline:
  //  XC  f32[2048][2048] 16.78MB: xc (GEMM1) -> conv reads -> S|P (scan p1/p2)
  //                               -> y (scan p3) -> GEMM4 A
  //  Z   f32[2048][2048] 16.78MB: z (GEMM1) -> scan p3 reads
  //  u   f32[2048][2048] 16.78MB: conv -> GEMM2/p1/p3 read
  //  xdbl f32[2048][96]   0.79MB
  //  W   16.78MB: [0..8.39M) w1t bf16 (dead after GEMM1) / delta bf16 (GEMM3)
  //               [8.39M..12.58M) H f32   [12.58M..16.77M) w4t bf16
  float* XC   = (float*)d_ws;
  float* Z    = XC + (size_t)NROW * DINNER;
  float* u    = Z  + (size_t)NROW * DINNER;
  float* xdbl = u  + (size_t)NROW * DINNER;
  char*  W    = (char*)(xdbl + (size_t)NROW * NPROJ);
  unsigned short* w1t     = (unsigned short*)W;
  unsigned short* delta16 = (unsigned short*)W;          // aliases w1t
  float*          Hsc     = (float*)(W + 8388608);
  unsigned short* w4t     = (unsigned short*)(W + 12582912);
  float* Ssc = XC;                                       // aliases xc region
  float* Psc = XC + (size_t)BSZ * NCHUNK * DINNER * DSTATE;

  dim3 blk(256);

  // weight transpose+cast (w4t slice is disjoint from w1t/delta/H -> safe early)
  transpose_cast_k<<<dim3((2*DINNER)/32, DIMX/32), blk, 0, stream>>>(
      in_proj_w, w1t, DIMX, 2*DINNER);
  transpose_cast_k<<<dim3(DIMX/32, DINNER/32), blk, 0, stream>>>(
      out_proj_w, w4t, DINNER, DIMX);

  // GEMM1 (MFMA): [xc|z] = x @ in_proj_w  (2048 x 4096 x 1024), split C-write
  gemm_mfma_k<128><<<dim3((2*DINNER)/128, NROW/128), blk, 0, stream>>>(
      x, DIMX, w1t, DIMX, XC, Z, DINNER, DINNER, DIMX);

  // conv + silu -> u
  conv_silu_k<<<(NROW*DINNER)/256, blk, 0, stream>>>(XC, conv_w, conv_b, u);

  // GEMM2 (f32): x_dbl = u @ x_proj_w (2048 x 96 x 2048)
  gemm_k<0,0><<<dim3((NPROJ+63)/64, NROW/64), blk, 0, stream>>>(
      u, DINNER, x_proj_w, NPROJ, xdbl, NPROJ, NROW, NPROJ, DINNER, nullptr);

  // GEMM3 (f32, bf16 out): delta = softplus(dtr @ dt_proj_w + b) (2048x2048x64)
  gemm_k<1,1><<<dim3(DINNER/64, NROW/64), blk, 0, stream>>>(
      xdbl, NPROJ, dt_proj_w, DINNER, delta16, DINNER, NROW, DINNER, DTRANK, dt_proj_b);

  // chunked selective scan
  scan_p1<<<dim3(BSZ*128*NCHUNK), blk, 0, stream>>>(delta16, u, xdbl, A_log, Ssc, Psc);
  scan_p2<<<dim3((BSZ*DINNER*DSTATE)/256), blk, 0, stream>>>(Ssc, Psc, Hsc);
  scan_p3<<<dim3(BSZ*128*NCHUNK), blk, 0, stream>>>(
      delta16, u, Z, xdbl, A_log, Dp, Hsc, XC);

  // GEMM4 (MFMA): out = y @ out_proj_w (2048 x 1024 x 2048)
  gemm_mfma_k<64><<<dim3(DIMX/64, NROW/128), blk, 0, stream>>>(
      XC, DINNER, w4t, DINNER, out, out, 1<<30, DIMX, DINNER);
}

// Round 5
// 360.151 us; speedup vs baseline: 2.5290x; 1.2816x over previous
//
#include <hip/hip_runtime.h>
#include <hip/hip_bf16.h>

#define DIMX 1024
#define DSTATE 16
#define DCONV 4
#define DINNER 2048
#define DTRANK 64
#define BSZ 2
#define SEQL 1024
#define NROW (BSZ*SEQL)              // 2048
#define NPROJ (DTRANK + 2*DSTATE)    // 96
#define NCHUNK 16
#define CLEN 64                      // SEQL / NCHUNK
#define G2SPLIT 16                   // GEMM2 split-K factor
#define G2KLEN (DINNER / G2SPLIT)    // 128

typedef __bf16 bf16x8 __attribute__((ext_vector_type(8)));
typedef float f32x4 __attribute__((ext_vector_type(4)));
typedef unsigned short ushort8_t __attribute__((ext_vector_type(8)));

__device__ __forceinline__ float sigmoidf_(float x){ return 1.0f/(1.0f+__expf(-x)); }
__device__ __forceinline__ unsigned short f2bf(float f){
  union { float f; unsigned int i; } c; c.f = f;
  unsigned int r = (c.i + 0x7FFFu + ((c.i >> 16) & 1u)) >> 16;
  return (unsigned short)r;
}
__device__ __forceinline__ float bf2f(unsigned short u){
  union { unsigned int i; float f; } c; c.i = ((unsigned int)u) << 16; return c.f;
}

// ---------------------------------------------------------------------------
// Transpose + cast: w (K x N, f32) -> wt (N x K, bf16). Grid (N/32, K/32).
// ---------------------------------------------------------------------------
__global__ __launch_bounds__(256) void transpose_cast_k(
    const float* __restrict__ w, unsigned short* __restrict__ wt, int K, int N)
{
  __shared__ unsigned short T[32][33];
  const int nT = blockIdx.x * 32, kT = blockIdx.y * 32;
  const int tx = threadIdx.x & 31, ty = threadIdx.x >> 5;   // ty 0..7
  #pragma unroll
  for (int i = 0; i < 4; i++) {
    const int k = kT + ty + i*8;
    T[tx][ty + i*8] = f2bf(w[(size_t)k * N + nT + tx]);
  }
  __syncthreads();
  #pragma unroll
  for (int i = 0; i < 4; i++) {
    const int n = nT + ty + i*8;
    wt[(size_t)n * K + kT + tx] = T[ty + i*8][tx];
  }
}

// ---------------------------------------------------------------------------
// MFMA GEMM: C = A(f32, cast->bf16 in staging) @ BT^T;  BT (N x K) bf16.
// BM=128, BK=32, BN in {128,64}. 256 thr = 4 waves. LDS row stride 40 bf16.
// C-write splits at column splitN: col<splitN -> C0, else C1 (col-splitN).
// ---------------------------------------------------------------------------
template<int BN>
__global__ __launch_bounds__(256) void gemm_mfma_k(
    const float* __restrict__ A, int lda,
    const unsigned short* __restrict__ BT, int ldb,
    float* __restrict__ C0, float* __restrict__ C1, int splitN, int ldc,
    int K)
{
  constexpr int BM = 128;
  constexpr int WCOLS = BN / 64;
  constexpr int WROWS = 4 / WCOLS;
  constexpr int WM = BM / WROWS;
  constexpr int MI = WM / 16;
  constexpr int NI = 4;

  __shared__ unsigned short As[BM * 40];
  __shared__ unsigned short Bs[BN * 40];

  const int tid = threadIdx.x;
  const int w = tid >> 6, lane = tid & 63;
  const int quad = lane >> 4, lrow = lane & 15;
  const int waveM = w % WROWS, waveN = w / WROWS;
  const int mOff = waveM * WM, nOff = waveN * 64;
  const int rowTile = blockIdx.y * BM, colTile = blockIdx.x * BN;

  f32x4 acc[MI][NI] = {};

  const int sr = tid >> 2;          // 0..63
  const int sc = (tid & 3) * 8;     // 0,8,16,24

  for (int k0 = 0; k0 < K; k0 += 32) {
    #pragma unroll
    for (int i = 0; i < BM/64; i++) {
      const int r = sr + i*64;
      const float* src = A + (size_t)(rowTile + r) * lda + k0 + sc;
      float4 v0 = *(const float4*)src;
      float4 v1 = *(const float4*)(src + 4);
      ushort8_t t;
      t[0]=f2bf(v0.x); t[1]=f2bf(v0.y); t[2]=f2bf(v0.z); t[3]=f2bf(v0.w);
      t[4]=f2bf(v1.x); t[5]=f2bf(v1.y); t[6]=f2bf(v1.z); t[7]=f2bf(v1.w);
      *(ushort8_t*)&As[r*40 + sc] = t;
    }
    #pragma unroll
    for (int i = 0; i < BN/64; i++) {
      const int r = sr + i*64;
      *(ushort8_t*)&Bs[r*40 + sc] =
          *(const ushort8_t*)(BT + (size_t)(colTile + r) * ldb + k0 + sc);
    }
    __syncthreads();

    bf16x8 af[MI], bfr[NI];
    #pragma unroll
    for (int mi = 0; mi < MI; mi++)
      af[mi] = *(const bf16x8*)&As[(mOff + mi*16 + lrow)*40 + quad*8];
    #pragma unroll
    for (int ni = 0; ni < NI; ni++)
      bfr[ni] = *(const bf16x8*)&Bs[(nOff + ni*16 + lrow)*40 + quad*8];
    #pragma unroll
    for (int mi = 0; mi < MI; mi++)
      #pragma unroll
      for (int ni = 0; ni < NI; ni++)
        acc[mi][ni] = __builtin_amdgcn_mfma_f32_16x16x32_bf16(
            af[mi], bfr[ni], acc[mi][ni], 0, 0, 0);
    __syncthreads();
  }

  #pragma unroll
  for (int mi = 0; mi < MI; mi++) {
    #pragma unroll
    for (int ni = 0; ni < NI; ni++) {
      const int row = rowTile + mOff + mi*16 + quad*4;
      const int col = colTile + nOff + ni*16 + lrow;
      float* Cb = (col < splitN) ? C0 : C1;
      const int cc = (col < splitN) ? col : col - splitN;
      #pragma unroll
      for (int r = 0; r < 4; r++)
        Cb[(size_t)(row + r) * ldc + cc] = acc[mi][ni][r];
    }
  }
}

// ---------------------------------------------------------------------------
// Tiled f32 GEMM. OUT_BF16: store bf16. EPI==1: softplus+bias.
// KCHUNK>0: split-K — blockIdx.z selects K range [z*KCHUNK, (z+1)*KCHUNK),
// output goes to partial slice Cp + z*M*ldc (f32 only).
// ---------------------------------------------------------------------------
template<int EPI, int OUT_BF16, int KCHUNK>
__global__ __launch_bounds__(256) void gemm_k(
    const float* __restrict__ Ap, int lda,
    const float* __restrict__ Bp, int ldb,
    void* __restrict__ Cp, int ldc,
    int M, int N, int K,
    const float* __restrict__ bias)
{
  __shared__ float As[16][64];
  __shared__ float Bs[16][64];
  const int tid = threadIdx.x;
  const int tx = tid & 15, ty = tid >> 4;
  const int rowTile = blockIdx.y * 64;
  const int colTile = blockIdx.x * 64;

  int kBeg = 0, kEnd = K;
  float* Cout = (float*)Cp;
  if constexpr (KCHUNK > 0) {
    kBeg = blockIdx.z * KCHUNK;
    kEnd = kBeg + KCHUNK;
    Cout += (size_t)blockIdx.z * M * ldc;
  }

  const int ar = tid >> 2;
  const int ak = (tid & 3) * 4;
  const int bk = tid >> 4;
  const int bn = (tid & 15) * 4;

  float acc[4][4] = {};

  for (int k0 = kBeg; k0 < kEnd; k0 += 16) {
    {
      const int r = rowTile + ar;
      float4 av = *(const float4*)(Ap + (size_t)r * lda + k0 + ak);
      As[ak+0][ar] = av.x; As[ak+1][ar] = av.y;
      As[ak+2][ar] = av.z; As[ak+3][ar] = av.w;
    }
    {
      const int kk = k0 + bk;
      const int c = colTile + bn;
      float4 bv;
      if (c + 3 < N) {
        bv = *(const float4*)(Bp + (size_t)kk * ldb + c);
      } else {
        bv.x = (c+0 < N) ? Bp[(size_t)kk*ldb + c+0] : 0.f;
        bv.y = (c+1 < N) ? Bp[(size_t)kk*ldb + c+1] : 0.f;
        bv.z = (c+2 < N) ? Bp[(size_t)kk*ldb + c+2] : 0.f;
        bv.w = (c+3 < N) ? Bp[(size_t)kk*ldb + c+3] : 0.f;
      }
      *(float4*)&Bs[bk][bn] = bv;
    }
    __syncthreads();
    #pragma unroll
    for (int kk = 0; kk < 16; kk++) {
      float4 a4 = *(const float4*)&As[kk][ty*4];
      float4 b4 = *(const float4*)&Bs[kk][tx*4];
      float a[4] = {a4.x, a4.y, a4.z, a4.w};
      float b[4] = {b4.x, b4.y, b4.z, b4.w};
      #pragma unroll
      for (int i = 0; i < 4; i++)
        #pragma unroll
        for (int j = 0; j < 4; j++)
          acc[i][j] += a[i] * b[j];
    }
    __syncthreads();
  }

  #pragma unroll
  for (int i = 0; i < 4; i++) {
    const int r = rowTile + ty*4 + i;
    #pragma unroll
    for (int j = 0; j < 4; j++) {
      const int c = colTile + tx*4 + j;
      if (c >= N) continue;
      float v = acc[i][j];
      if constexpr (EPI == 1) {
        v += bias[c];
        v = (v > 20.f) ? v : log1pf(__expf(v));
      }
      if constexpr (OUT_BF16) ((unsigned short*)Cp)[(size_t)r*ldc + c] = f2bf(v);
      else                    Cout[(size_t)r*ldc + c] = v;
    }
  }
}

// ---------------------------------------------------------------------------
// Sum G2SPLIT partial C slices: outp[i] = sum_z part[z*n + i]. float4 ops.
// ---------------------------------------------------------------------------
__global__ __launch_bounds__(256) void reduce_split_k(
    const float* __restrict__ part, float* __restrict__ outp, int n4)
{
  const int i = blockIdx.x * 256 + threadIdx.x;
  if (i >= n4) return;
  float4 s = *(const float4*)(part + (size_t)i * 4);
  #pragma unroll
  for (int z = 1; z < G2SPLIT; z++) {
    float4 v = *(const float4*)(part + (size_t)z * n4 * 4 + (size_t)i * 4);
    s.x += v.x; s.y += v.y; s.z += v.z; s.w += v.w;
  }
  *(float4*)(outp + (size_t)i * 4) = s;
}

// ---------------------------------------------------------------------------
// Causal depthwise conv (width 4) + SiLU. xc: (NROW x 2048 f32, contiguous).
// ---------------------------------------------------------------------------
__global__ __launch_bounds__(256) void conv_silu_k(
    const float* __restrict__ xc,
    const float* __restrict__ conv_w,
    const float* __restrict__ conv_b,
    float* __restrict__ u)
{
  const int idx = blockIdx.x * 256 + threadIdx.x;
  if (idx >= NROW * DINNER) return;
  const int d = idx & (DINNER - 1);
  const int row = idx >> 11;
  const int l = row & (SEQL - 1);
  float acc = conv_b[d];
  #pragma unroll
  for (int k = 0; k < DCONV; k++) {
    const int ls = l + k - (DCONV - 1);
    if (ls >= 0)
      acc += xc[(size_t)(row + k - (DCONV - 1)) * DINNER + d] * conv_w[d*DCONV + k];
  }
  u[idx] = acc * sigmoidf_(acc);
}

// ---------------------------------------------------------------------------
// Chunked parallel scan (3 phases), as in R3 (verified).
// ---------------------------------------------------------------------------
__global__ __launch_bounds__(256) void scan_p1(
    const unsigned short* __restrict__ delta16,
    const float* __restrict__ u,
    const float* __restrict__ xdbl,
    const float* __restrict__ A_log,
    float* __restrict__ S, float* __restrict__ P)
{
  const int c = blockIdx.x & 15;
  const int dg = (blockIdx.x >> 4) & 127;
  const int b = blockIdx.x >> 11;
  const int dBase = dg * 16;
  const int tid = threadIdx.x;
  const int g = tid >> 4, n = tid & 15;
  const int d = dBase + g;
  const float Aval = -__expf(A_log[d*DSTATE + n]);

  __shared__ float delta_s[CLEN][16], u_s[CLEN][16], Bm_s[CLEN][16];
  const int t4 = tid >> 2, j4 = (tid & 3) * 4;
  const size_t rowL = (size_t)(b*SEQL + c*CLEN + t4);
  {
    ushort4 dv = *(const ushort4*)&delta16[rowL*DINNER + dBase + j4];
    delta_s[t4][j4+0] = bf2f(dv.x); delta_s[t4][j4+1] = bf2f(dv.y);
    delta_s[t4][j4+2] = bf2f(dv.z); delta_s[t4][j4+3] = bf2f(dv.w);
  }
  *(float4*)&u_s[t4][j4]  = *(const float4*)&u[rowL*DINNER + dBase + j4];
  *(float4*)&Bm_s[t4][j4] = *(const float4*)&xdbl[rowL*NPROJ + DTRANK + j4];
  __syncthreads();

  float h = 0.f, sumd = 0.f;
  #pragma unroll 4
  for (int t = 0; t < CLEN; t++) {
    const float dlt = delta_s[t][g];
    const float a = __expf(dlt * Aval);
    h = a * h + (dlt * u_s[t][g]) * Bm_s[t][n];
    sumd += dlt;
  }
  const size_t idx = ((size_t)(b*NCHUNK + c) * DINNER + d) * DSTATE + n;
  S[idx] = h;
  P[idx] = __expf(Aval * sumd);
}

__global__ __launch_bounds__(256) void scan_p2(
    const float* __restrict__ S, const float* __restrict__ P,
    float* __restrict__ H)
{
  const int idx = blockIdx.x * 256 + threadIdx.x;   // (b,d,n): 65536
  const int n = idx & 15, d = (idx >> 4) & (DINNER-1), b = idx >> 15;
  float h = 0.f;
  #pragma unroll
  for (int c = 0; c < NCHUNK; c++) {
    const size_t base = ((size_t)(b*NCHUNK + c) * DINNER + d) * DSTATE + n;
    H[base] = h;                       // chunk-start state
    h = P[base] * h + S[base];
  }
}

__global__ __launch_bounds__(256) void scan_p3(
    const unsigned short* __restrict__ delta16,
    const float* __restrict__ u,
    const float* __restrict__ Z,
    const float* __restrict__ xdbl,
    const float* __restrict__ A_log,
    const float* __restrict__ Dp,
    const float* __restrict__ H,
    float* __restrict__ Y)
{
  const int c = blockIdx.x & 15;
  const int dg = (blockIdx.x >> 4) & 127;
  const int b = blockIdx.x >> 11;
  const int dBase = dg * 16;
  const int tid = threadIdx.x;
  const int g = tid >> 4, n = tid & 15;
  const int d = dBase + g;
  const float Aval = -__expf(A_log[d*DSTATE + n]);
  const float Dval = Dp[d];

  __shared__ float delta_s[CLEN][16], u_s[CLEN][16], z_s[CLEN][16];
  __shared__ float Bm_s[CLEN][16], Cm_s[CLEN][16], y_s[CLEN][16];
  const int t4 = tid >> 2, j4 = (tid & 3) * 4;
  const size_t rowL = (size_t)(b*SEQL + c*CLEN + t4);
  {
    ushort4 dv = *(const ushort4*)&delta16[rowL*DINNER + dBase + j4];
    delta_s[t4][j4+0] = bf2f(dv.x); delta_s[t4][j4+1] = bf2f(dv.y);
    delta_s[t4][j4+2] = bf2f(dv.z); delta_s[t4][j4+3] = bf2f(dv.w);
  }
  *(float4*)&u_s[t4][j4]  = *(const float4*)&u[rowL*DINNER + dBase + j4];
  *(float4*)&z_s[t4][j4]  = *(const float4*)&Z[rowL*DINNER + dBase + j4];
  *(float4*)&Bm_s[t4][j4] = *(const float4*)&xdbl[rowL*NPROJ + DTRANK + j4];
  *(float4*)&Cm_s[t4][j4] = *(const float4*)&xdbl[rowL*NPROJ + DTRANK + DSTATE + j4];
  __syncthreads();

  float h = H[((size_t)(b*NCHUNK + c) * DINNER + d) * DSTATE + n];
  for (int t = 0; t < CLEN; t++) {
    const float dlt = delta_s[t][g];
    const float uu  = u_s[t][g];
    const float a = __expf(dlt * Aval);
    h = a * h + (dlt * uu) * Bm_s[t][n];
    float p = h * Cm_s[t][n];
    p += __shfl_xor(p, 8);
    p += __shfl_xor(p, 4);
    p += __shfl_xor(p, 2);
    p += __shfl_xor(p, 1);
    if (n == 0) {
      const float zv = z_s[t][g];
      y_s[t][g] = (p + uu * Dval) * (zv * sigmoidf_(zv));
    }
  }
  __syncthreads();
  *(float4*)&Y[rowL*DINNER + dBase + j4] = *(const float4*)&y_s[t4][j4];
}

// ---------------------------------------------------------------------------
extern "C" void kernel_launch(void* const* d_in, const int* in_sizes, int n_in,
                              void* d_out, int out_size, void* d_ws, size_t ws_size,
                              hipStream_t stream) {
  const float* x         = (const float*)d_in[0];
  const float* in_proj_w = (const float*)d_in[2];
  const float* conv_w    = (const float*)d_in[3];
  const float* conv_b    = (const float*)d_in[4];
  const float* x_proj_w  = (const float*)d_in[5];
  const float* dt_proj_w = (const float*)d_in[6];
  const float* dt_proj_b = (const float*)d_in[7];
  const float* A_log     = (const float*)d_in[8];
  const float* Dp        = (const float*)d_in[9];
  const float* out_proj_w= (const float*)d_in[10];
  float* out = (float*)d_out;

  // ws layout — EXACTLY the R2-proven 67,895,296 bytes. Aliasing timeline:
  //  XC  f32[2048][2048] 16.78MB: xc (GEMM1) -> conv reads ->
  //      GEMM2 split-K partials (12.58MB) -> S|P (scan p1/p2, 8MB) ->
  //      y (scan p3) -> GEMM4 A
  //  Z   f32[2048][2048] 16.78MB: z (GEMM1) -> scan p3 reads
  //  u   f32[2048][2048] 16.78MB: conv -> GEMM2/p1/p3 read
  //  xdbl f32[2048][96]   0.79MB
  //  W   16.78MB: [0..8.39M) w1t bf16 (dead after GEMM1) / delta bf16 (GEMM3)
  //               [8.39M..12.58M) H f32   [12.58M..16.77M) w4t bf16
  float* XC   = (float*)d_ws;
  float* Z    = XC + (size_t)NROW * DINNER;
  float* u    = Z  + (size_t)NROW * DINNER;
  float* xdbl = u  + (size_t)NROW * DINNER;
  char*  W    = (char*)(xdbl + (size_t)NROW * NPROJ);
  unsigned short* w1t     = (unsigned short*)W;
  unsigned short* delta16 = (unsigned short*)W;          // aliases w1t
  float*          Hsc     = (float*)(W + 8388608);
  unsigned short* w4t     = (unsigned short*)(W + 12582912);
  float* g2part = XC;                                    // 16 x 2048 x 96 f32
  float* Ssc = XC;                                       // scan p1 S (4MB)
  float* Psc = XC + (size_t)BSZ * NCHUNK * DINNER * DSTATE;  // scan p1 P (4MB)

  dim3 blk(256);

  // weight transpose+cast
  transpose_cast_k<<<dim3((2*DINNER)/32, DIMX/32), blk, 0, stream>>>(
      in_proj_w, w1t, DIMX, 2*DINNER);
  transpose_cast_k<<<dim3(DIMX/32, DINNER/32), blk, 0, stream>>>(
      out_proj_w, w4t, DINNER, DIMX);

  // GEMM1 (MFMA): [xc|z] = x @ in_proj_w  (2048 x 4096 x 1024), split C-write
  gemm_mfma_k<128><<<dim3((2*DINNER)/128, NROW/128), blk, 0, stream>>>(
      x, DIMX, w1t, DIMX, XC, Z, DINNER, DINNER, DIMX);

  // conv + silu -> u
  conv_silu_k<<<(NROW*DINNER)/256, blk, 0, stream>>>(XC, conv_w, conv_b, u);

  // GEMM2 (f32, split-K 16): partials = u @ x_proj_w slices, then reduce
  gemm_k<0,0,G2KLEN><<<dim3((NPROJ+63)/64, NROW/64, G2SPLIT), blk, 0, stream>>>(
      u, DINNER, x_proj_w, NPROJ, g2part, NPROJ, NROW, NPROJ, DINNER, nullptr);
  reduce_split_k<<<dim3((NROW*NPROJ/4 + 255)/256), blk, 0, stream>>>(
      g2part, xdbl, NROW*NPROJ/4);

  // GEMM3 (f32, bf16 out): delta = softplus(dtr @ dt_proj_w + b) (2048x2048x64)
  gemm_k<1,1,0><<<dim3(DINNER/64, NROW/64), blk, 0, stream>>>(
      xdbl, NPROJ, dt_proj_w, DINNER, delta16, DINNER, NROW, DINNER, DTRANK, dt_proj_b);

  // chunked selective scan
  scan_p1<<<dim3(BSZ*128*NCHUNK), blk, 0, stream>>>(delta16, u, xdbl, A_log, Ssc, Psc);
  scan_p2<<<dim3((BSZ*DINNER*DSTATE)/256), blk, 0, stream>>>(Ssc, Psc, Hsc);
  scan_p3<<<dim3(BSZ*128*NCHUNK), blk, 0, stream>>>(
      delta16, u, Z, xdbl, A_log, Dp, Hsc, XC);

  // GEMM4 (MFMA): out = y @ out_proj_w (2048 x 1024 x 2048)
  gemm_mfma_k<64><<<dim3(DIMX/64, NROW/128), blk, 0, stream>>>(
      XC, DINNER, w4t, DINNER, out, out, 1<<30, DIMX, DINNER);
}

// Round 6
// 326.157 us; speedup vs baseline: 2.7925x; 1.1042x over previous
//
#include <hip/hip_runtime.h>
#include <hip/hip_bf16.h>

#define DIMX 1024
#define DSTATE 16
#define DCONV 4
#define DINNER 2048
#define DTRANK 64
#define BSZ 2
#define SEQL 1024
#define NROW (BSZ*SEQL)              // 2048
#define NPROJ (DTRANK + 2*DSTATE)    // 96
#define NCHUNK 16
#define CLEN 64                      // SEQL / NCHUNK
#define G2SPLIT 16                   // GEMM2 split-K factor
#define G2KLEN (DINNER / G2SPLIT)    // 128
#define LSTR 68                      // LDS row stride (floats): pad 64->68

typedef __bf16 bf16x8 __attribute__((ext_vector_type(8)));
typedef float f32x4 __attribute__((ext_vector_type(4)));
typedef unsigned short ushort8_t __attribute__((ext_vector_type(8)));

#define LOG2E 1.44269504088896340736f

__device__ __forceinline__ float sigmoidf_(float x){ return 1.0f/(1.0f+__expf(-x)); }
__device__ __forceinline__ unsigned short f2bf(float f){
  union { float f; unsigned int i; } c; c.f = f;
  unsigned int r = (c.i + 0x7FFFu + ((c.i >> 16) & 1u)) >> 16;
  return (unsigned short)r;
}
__device__ __forceinline__ float bf2f(unsigned short u){
  union { unsigned int i; float f; } c; c.i = ((unsigned int)u) << 16; return c.f;
}

// DPP row_shr add: p += shifted(p). After shr 1,2,4,8 lane15 of each 16-lane
// row holds the row sum. bound_ctrl=1 -> shifted-in lanes read 0.
template<int CTRL>
__device__ __forceinline__ float dpp_add(float p){
  int v = __builtin_amdgcn_update_dpp(0, __float_as_int(p), CTRL, 0xf, 0xf, true);
  return p + __int_as_float(v);
}
__device__ __forceinline__ float row_sum16(float p){
  p = dpp_add<0x111>(p);   // row_shr:1
  p = dpp_add<0x112>(p);   // row_shr:2
  p = dpp_add<0x114>(p);   // row_shr:4
  p = dpp_add<0x118>(p);   // row_shr:8 -> lane n==15 has sum
  return p;
}

// ---------------------------------------------------------------------------
// Transpose + cast: w (K x N, f32) -> wt (N x K, bf16). Grid (N/32, K/32).
// ---------------------------------------------------------------------------
__global__ __launch_bounds__(256) void transpose_cast_k(
    const float* __restrict__ w, unsigned short* __restrict__ wt, int K, int N)
{
  __shared__ unsigned short T[32][33];
  const int nT = blockIdx.x * 32, kT = blockIdx.y * 32;
  const int tx = threadIdx.x & 31, ty = threadIdx.x >> 5;   // ty 0..7
  #pragma unroll
  for (int i = 0; i < 4; i++) {
    const int k = kT + ty + i*8;
    T[tx][ty + i*8] = f2bf(w[(size_t)k * N + nT + tx]);
  }
  __syncthreads();
  #pragma unroll
  for (int i = 0; i < 4; i++) {
    const int n = nT + ty + i*8;
    wt[(size_t)n * K + kT + tx] = T[ty + i*8][tx];
  }
}

// ---------------------------------------------------------------------------
// MFMA GEMM: C = A(f32, cast->bf16 in staging) @ BT^T;  BT (N x K) bf16.
// BM=128, BK=32, BN in {128,64}. 256 thr = 4 waves. LDS row stride 40 bf16.
// C-write splits at column splitN: col<splitN -> C0, else C1 (col-splitN).
// ---------------------------------------------------------------------------
template<int BN>
__global__ __launch_bounds__(256) void gemm_mfma_k(
    const float* __restrict__ A, int lda,
    const unsigned short* __restrict__ BT, int ldb,
    float* __restrict__ C0, float* __restrict__ C1, int splitN, int ldc,
    int K)
{
  constexpr int BM = 128;
  constexpr int WCOLS = BN / 64;
  constexpr int WROWS = 4 / WCOLS;
  constexpr int WM = BM / WROWS;
  constexpr int MI = WM / 16;
  constexpr int NI = 4;

  __shared__ unsigned short As[BM * 40];
  __shared__ unsigned short Bs[BN * 40];

  const int tid = threadIdx.x;
  const int w = tid >> 6, lane = tid & 63;
  const int quad = lane >> 4, lrow = lane & 15;
  const int waveM = w % WROWS, waveN = w / WROWS;
  const int mOff = waveM * WM, nOff = waveN * 64;
  const int rowTile = blockIdx.y * BM, colTile = blockIdx.x * BN;

  f32x4 acc[MI][NI] = {};

  const int sr = tid >> 2;          // 0..63
  const int sc = (tid & 3) * 8;     // 0,8,16,24

  for (int k0 = 0; k0 < K; k0 += 32) {
    #pragma unroll
    for (int i = 0; i < BM/64; i++) {
      const int r = sr + i*64;
      const float* src = A + (size_t)(rowTile + r) * lda + k0 + sc;
      float4 v0 = *(const float4*)src;
      float4 v1 = *(const float4*)(src + 4);
      ushort8_t t;
      t[0]=f2bf(v0.x); t[1]=f2bf(v0.y); t[2]=f2bf(v0.z); t[3]=f2bf(v0.w);
      t[4]=f2bf(v1.x); t[5]=f2bf(v1.y); t[6]=f2bf(v1.z); t[7]=f2bf(v1.w);
      *(ushort8_t*)&As[r*40 + sc] = t;
    }
    #pragma unroll
    for (int i = 0; i < BN/64; i++) {
      const int r = sr + i*64;
      *(ushort8_t*)&Bs[r*40 + sc] =
          *(const ushort8_t*)(BT + (size_t)(colTile + r) * ldb + k0 + sc);
    }
    __syncthreads();

    bf16x8 af[MI], bfr[NI];
    #pragma unroll
    for (int mi = 0; mi < MI; mi++)
      af[mi] = *(const bf16x8*)&As[(mOff + mi*16 + lrow)*40 + quad*8];
    #pragma unroll
    for (int ni = 0; ni < NI; ni++)
      bfr[ni] = *(const bf16x8*)&Bs[(nOff + ni*16 + lrow)*40 + quad*8];
    #pragma unroll
    for (int mi = 0; mi < MI; mi++)
      #pragma unroll
      for (int ni = 0; ni < NI; ni++)
        acc[mi][ni] = __builtin_amdgcn_mfma_f32_16x16x32_bf16(
            af[mi], bfr[ni], acc[mi][ni], 0, 0, 0);
    __syncthreads();
  }

  #pragma unroll
  for (int mi = 0; mi < MI; mi++) {
    #pragma unroll
    for (int ni = 0; ni < NI; ni++) {
      const int row = rowTile + mOff + mi*16 + quad*4;
      const int col = colTile + nOff + ni*16 + lrow;
      float* Cb = (col < splitN) ? C0 : C1;
      const int cc = (col < splitN) ? col : col - splitN;
      #pragma unroll
      for (int r = 0; r < 4; r++)
        Cb[(size_t)(row + r) * ldc + cc] = acc[mi][ni][r];
    }
  }
}

// ---------------------------------------------------------------------------
// Tiled f32 GEMM. OUT_BF16: store bf16. EPI==1: softplus+bias.
// KCHUNK>0: split-K via blockIdx.z, partials at Cp + z*M*ldc.
// ---------------------------------------------------------------------------
template<int EPI, int OUT_BF16, int KCHUNK>
__global__ __launch_bounds__(256) void gemm_k(
    const float* __restrict__ Ap, int lda,
    const float* __restrict__ Bp, int ldb,
    void* __restrict__ Cp, int ldc,
    int M, int N, int K,
    const float* __restrict__ bias)
{
  __shared__ float As[16][64];
  __shared__ float Bs[16][64];
  const int tid = threadIdx.x;
  const int tx = tid & 15, ty = tid >> 4;
  const int rowTile = blockIdx.y * 64;
  const int colTile = blockIdx.x * 64;

  int kBeg = 0, kEnd = K;
  float* Cout = (float*)Cp;
  if constexpr (KCHUNK > 0) {
    kBeg = blockIdx.z * KCHUNK;
    kEnd = kBeg + KCHUNK;
    Cout += (size_t)blockIdx.z * M * ldc;
  }

  const int ar = tid >> 2;
  const int ak = (tid & 3) * 4;
  const int bk = tid >> 4;
  const int bn = (tid & 15) * 4;

  float acc[4][4] = {};

  for (int k0 = kBeg; k0 < kEnd; k0 += 16) {
    {
      const int r = rowTile + ar;
      float4 av = *(const float4*)(Ap + (size_t)r * lda + k0 + ak);
      As[ak+0][ar] = av.x; As[ak+1][ar] = av.y;
      As[ak+2][ar] = av.z; As[ak+3][ar] = av.w;
    }
    {
      const int kk = k0 + bk;
      const int c = colTile + bn;
      float4 bv;
      if (c + 3 < N) {
        bv = *(const float4*)(Bp + (size_t)kk * ldb + c);
      } else {
        bv.x = (c+0 < N) ? Bp[(size_t)kk*ldb + c+0] : 0.f;
        bv.y = (c+1 < N) ? Bp[(size_t)kk*ldb + c+1] : 0.f;
        bv.z = (c+2 < N) ? Bp[(size_t)kk*ldb + c+2] : 0.f;
        bv.w = (c+3 < N) ? Bp[(size_t)kk*ldb + c+3] : 0.f;
      }
      *(float4*)&Bs[bk][bn] = bv;
    }
    __syncthreads();
    #pragma unroll
    for (int kk = 0; kk < 16; kk++) {
      float4 a4 = *(const float4*)&As[kk][ty*4];
      float4 b4 = *(const float4*)&Bs[kk][tx*4];
      float a[4] = {a4.x, a4.y, a4.z, a4.w};
      float b[4] = {b4.x, b4.y, b4.z, b4.w};
      #pragma unroll
      for (int i = 0; i < 4; i++)
        #pragma unroll
        for (int j = 0; j < 4; j++)
          acc[i][j] += a[i] * b[j];
    }
    __syncthreads();
  }

  #pragma unroll
  for (int i = 0; i < 4; i++) {
    const int r = rowTile + ty*4 + i;
    #pragma unroll
    for (int j = 0; j < 4; j++) {
      const int c = colTile + tx*4 + j;
      if (c >= N) continue;
      float v = acc[i][j];
      if constexpr (EPI == 1) {
        v += bias[c];
        v = (v > 20.f) ? v : log1pf(__expf(v));
      }
      if constexpr (OUT_BF16) ((unsigned short*)Cp)[(size_t)r*ldc + c] = f2bf(v);
      else                    Cout[(size_t)r*ldc + c] = v;
    }
  }
}

// ---------------------------------------------------------------------------
// Sum G2SPLIT partial C slices.
// ---------------------------------------------------------------------------
__global__ __launch_bounds__(256) void reduce_split_k(
    const float* __restrict__ part, float* __restrict__ outp, int n4)
{
  const int i = blockIdx.x * 256 + threadIdx.x;
  if (i >= n4) return;
  float4 s = *(const float4*)(part + (size_t)i * 4);
  #pragma unroll
  for (int z = 1; z < G2SPLIT; z++) {
    float4 v = *(const float4*)(part + (size_t)z * n4 * 4 + (size_t)i * 4);
    s.x += v.x; s.y += v.y; s.z += v.z; s.w += v.w;
  }
  *(float4*)(outp + (size_t)i * 4) = s;
}

// ---------------------------------------------------------------------------
// Causal depthwise conv (width 4) + SiLU.
// ---------------------------------------------------------------------------
__global__ __launch_bounds__(256) void conv_silu_k(
    const float* __restrict__ xc,
    const float* __restrict__ conv_w,
    const float* __restrict__ conv_b,
    float* __restrict__ u)
{
  const int idx = blockIdx.x * 256 + threadIdx.x;
  if (idx >= NROW * DINNER) return;
  const int d = idx & (DINNER - 1);
  const int row = idx >> 11;
  const int l = row & (SEQL - 1);
  float acc = conv_b[d];
  #pragma unroll
  for (int k = 0; k < DCONV; k++) {
    const int ls = l + k - (DCONV - 1);
    if (ls >= 0)
      acc += xc[(size_t)(row + k - (DCONV - 1)) * DINNER + d] * conv_w[d*DCONV + k];
  }
  u[idx] = acc * sigmoidf_(acc);
}

// ---------------------------------------------------------------------------
// Chunked parallel scan, LDS-pipe-lean version.
// LDS layout [channel-or-state][t] stride 68 -> ds_read_b128 covers 4 t.
// Cross-lane reduce via DPP row_shr (VALU pipe, no LDS).
// ---------------------------------------------------------------------------
__global__ __launch_bounds__(256) void scan_p1(
    const unsigned short* __restrict__ delta16,
    const float* __restrict__ u,
    const float* __restrict__ xdbl,
    const float* __restrict__ A_log,
    float* __restrict__ S, float* __restrict__ P)
{
  const int c = blockIdx.x & 15;
  const int dg = (blockIdx.x >> 4) & 127;
  const int b = blockIdx.x >> 11;
  const int dBase = dg * 16;
  const int tid = threadIdx.x;
  const int g = tid >> 4, n = tid & 15;
  const int d = dBase + g;
  const float A2 = -__expf(A_log[d*DSTATE + n]) * LOG2E;  // exp(x*A)=exp2(x*A2)

  __shared__ float dlt_s[16][LSTR], du_s[16][LSTR], Bm_s[16][LSTR];

  const int t4 = tid >> 2, j4 = (tid & 3) * 4;
  const size_t rowL = (size_t)(b*SEQL + c*CLEN + t4);
  {
    ushort4 dv = *(const ushort4*)&delta16[rowL*DINNER + dBase + j4];
    float4  uv = *(const float4*)&u[rowL*DINNER + dBase + j4];
    float4  bv = *(const float4*)&xdbl[rowL*NPROJ + DTRANK + j4];
    const float dd[4] = {bf2f(dv.x), bf2f(dv.y), bf2f(dv.z), bf2f(dv.w)};
    const float uu[4] = {uv.x, uv.y, uv.z, uv.w};
    const float bb[4] = {bv.x, bv.y, bv.z, bv.w};
    #pragma unroll
    for (int i = 0; i < 4; i++) {
      dlt_s[j4+i][t4] = dd[i];
      du_s[j4+i][t4]  = dd[i] * uu[i];
      Bm_s[j4+i][t4]  = bb[i];
    }
  }
  __syncthreads();

  float h = 0.f, sumd = 0.f;
  for (int t0 = 0; t0 < CLEN; t0 += 4) {
    f32x4 dv  = *(const f32x4*)&dlt_s[g][t0];
    f32x4 duv = *(const f32x4*)&du_s[g][t0];
    f32x4 bv  = *(const f32x4*)&Bm_s[n][t0];
    #pragma unroll
    for (int i = 0; i < 4; i++) {
      const float a = exp2f(dv[i] * A2);
      h = a * h + duv[i] * bv[i];
      sumd += dv[i];
    }
  }
  const size_t idx = ((size_t)(b*NCHUNK + c) * DINNER + d) * DSTATE + n;
  S[idx] = h;
  P[idx] = exp2f(A2 * sumd);
}

__global__ __launch_bounds__(256) void scan_p2(
    const float* __restrict__ S, const float* __restrict__ P,
    float* __restrict__ H)
{
  const int idx = blockIdx.x * 256 + threadIdx.x;   // (b,d,n): 65536
  const int n = idx & 15, d = (idx >> 4) & (DINNER-1), b = idx >> 15;
  float h = 0.f;
  #pragma unroll
  for (int c = 0; c < NCHUNK; c++) {
    const size_t base = ((size_t)(b*NCHUNK + c) * DINNER + d) * DSTATE + n;
    H[base] = h;                       // chunk-start state
    h = P[base] * h + S[base];
  }
}

__global__ __launch_bounds__(256) void scan_p3(
    const unsigned short* __restrict__ delta16,
    const float* __restrict__ u,
    const float* __restrict__ Z,
    const float* __restrict__ xdbl,
    const float* __restrict__ A_log,
    const float* __restrict__ Dp,
    const float* __restrict__ H,
    float* __restrict__ Y)
{
  const int c = blockIdx.x & 15;
  const int dg = (blockIdx.x >> 4) & 127;
  const int b = blockIdx.x >> 11;
  const int dBase = dg * 16;
  const int tid = threadIdx.x;
  const int g = tid >> 4, n = tid & 15;
  const int d = dBase + g;
  const float A2 = -__expf(A_log[d*DSTATE + n]) * LOG2E;

  __shared__ float dlt_s[16][LSTR], du_s[16][LSTR];
  __shared__ float Bm_s[16][LSTR], Cm_s[16][LSTR], y_s[16][LSTR];

  const int t4 = tid >> 2, j4 = (tid & 3) * 4;
  const size_t rowL = (size_t)(b*SEQL + c*CLEN + t4);
  {
    ushort4 dv = *(const ushort4*)&delta16[rowL*DINNER + dBase + j4];
    float4  uv = *(const float4*)&u[rowL*DINNER + dBase + j4];
    float4  bv = *(const float4*)&xdbl[rowL*NPROJ + DTRANK + j4];
    float4  cv = *(const float4*)&xdbl[rowL*NPROJ + DTRANK + DSTATE + j4];
    const float dd[4] = {bf2f(dv.x), bf2f(dv.y), bf2f(dv.z), bf2f(dv.w)};
    const float uu[4] = {uv.x, uv.y, uv.z, uv.w};
    const float bb[4] = {bv.x, bv.y, bv.z, bv.w};
    const float cc[4] = {cv.x, cv.y, cv.z, cv.w};
    #pragma unroll
    for (int i = 0; i < 4; i++) {
      dlt_s[j4+i][t4] = dd[i];
      du_s[j4+i][t4]  = dd[i] * uu[i];
      Bm_s[j4+i][t4]  = bb[i];
      Cm_s[j4+i][t4]  = cc[i];
    }
  }
  __syncthreads();

  float h = H[((size_t)(b*NCHUNK + c) * DINNER + d) * DSTATE + n];
  for (int t0 = 0; t0 < CLEN; t0 += 4) {
    f32x4 dv  = *(const f32x4*)&dlt_s[g][t0];
    f32x4 duv = *(const f32x4*)&du_s[g][t0];
    f32x4 bv  = *(const f32x4*)&Bm_s[n][t0];
    f32x4 cv  = *(const f32x4*)&Cm_s[n][t0];
    f32x4 yq;
    #pragma unroll
    for (int i = 0; i < 4; i++) {
      const float a = exp2f(dv[i] * A2);
      h = a * h + duv[i] * bv[i];
      yq[i] = row_sum16(h * cv[i]);    // lane n==15 holds the sum
    }
    if (n == 15) *(f32x4*)&y_s[g][t0] = yq;
  }
  __syncthreads();

  // store stage: epilogue (p + u*D) * silu(z), vectorized global I/O
  {
    float4 uv = *(const float4*)&u[rowL*DINNER + dBase + j4];
    float4 zv = *(const float4*)&Z[rowL*DINNER + dBase + j4];
    float4 Dv = *(const float4*)&Dp[dBase + j4];
    float4 yo;
    const float zz[4] = {zv.x, zv.y, zv.z, zv.w};
    const float us[4] = {uv.x, uv.y, uv.z, uv.w};
    const float ds[4] = {Dv.x, Dv.y, Dv.z, Dv.w};
    float yy[4];
    #pragma unroll
    for (int i = 0; i < 4; i++) {
      const float p = y_s[j4+i][t4];
      yy[i] = (p + us[i]*ds[i]) * (zz[i] * sigmoidf_(zz[i]));
    }
    yo.x = yy[0]; yo.y = yy[1]; yo.z = yy[2]; yo.w = yy[3];
    *(float4*)&Y[rowL*DINNER + dBase + j4] = yo;
  }
}

// ---------------------------------------------------------------------------
extern "C" void kernel_launch(void* const* d_in, const int* in_sizes, int n_in,
                              void* d_out, int out_size, void* d_ws, size_t ws_size,
                              hipStream_t stream) {
  const float* x         = (const float*)d_in[0];
  const float* in_proj_w = (const float*)d_in[2];
  const float* conv_w    = (const float*)d_in[3];
  const float* conv_b    = (const float*)d_in[4];
  const float* x_proj_w  = (const float*)d_in[5];
  const float* dt_proj_w = (const float*)d_in[6];
  const float* dt_proj_b = (const float*)d_in[7];
  const float* A_log     = (const float*)d_in[8];
  const float* Dp        = (const float*)d_in[9];
  const float* out_proj_w= (const float*)d_in[10];
  float* out = (float*)d_out;

  // ws layout — EXACTLY the R2-proven 67,895,296 bytes (see R4 timeline).
  float* XC   = (float*)d_ws;
  float* Z    = XC + (size_t)NROW * DINNER;
  float* u    = Z  + (size_t)NROW * DINNER;
  float* xdbl = u  + (size_t)NROW * DINNER;
  char*  W    = (char*)(xdbl + (size_t)NROW * NPROJ);
  unsigned short* w1t     = (unsigned short*)W;
  unsigned short* delta16 = (unsigned short*)W;          // aliases w1t
  float*          Hsc     = (float*)(W + 8388608);
  unsigned short* w4t     = (unsigned short*)(W + 12582912);
  float* g2part = XC;                                    // 16 x 2048 x 96 f32
  float* Ssc = XC;                                       // scan p1 S (4MB)
  float* Psc = XC + (size_t)BSZ * NCHUNK * DINNER * DSTATE;  // scan p1 P (4MB)

  dim3 blk(256);

  transpose_cast_k<<<dim3((2*DINNER)/32, DIMX/32), blk, 0, stream>>>(
      in_proj_w, w1t, DIMX, 2*DINNER);
  transpose_cast_k<<<dim3(DIMX/32, DINNER/32), blk, 0, stream>>>(
      out_proj_w, w4t, DINNER, DIMX);

  // GEMM1 (MFMA): [xc|z] = x @ in_proj_w  (2048 x 4096 x 1024), split C-write
  gemm_mfma_k<128><<<dim3((2*DINNER)/128, NROW/128), blk, 0, stream>>>(
      x, DIMX, w1t, DIMX, XC, Z, DINNER, DINNER, DIMX);

  conv_silu_k<<<(NROW*DINNER)/256, blk, 0, stream>>>(XC, conv_w, conv_b, u);

  // GEMM2 (f32, split-K 16)
  gemm_k<0,0,G2KLEN><<<dim3((NPROJ+63)/64, NROW/64, G2SPLIT), blk, 0, stream>>>(
      u, DINNER, x_proj_w, NPROJ, g2part, NPROJ, NROW, NPROJ, DINNER, nullptr);
  reduce_split_k<<<dim3((NROW*NPROJ/4 + 255)/256), blk, 0, stream>>>(
      g2part, xdbl, NROW*NPROJ/4);

  // GEMM3 (f32, bf16 out): delta = softplus(dtr @ dt_proj_w + b)
  gemm_k<1,1,0><<<dim3(DINNER/64, NROW/64), blk, 0, stream>>>(
      xdbl, NPROJ, dt_proj_w, DINNER, delta16, DINNER, NROW, DINNER, DTRANK, dt_proj_b);

  // chunked selective scan
  scan_p1<<<dim3(BSZ*128*NCHUNK), blk, 0, stream>>>(delta16, u, xdbl, A_log, Ssc, Psc);
  scan_p2<<<dim3((BSZ*DINNER*DSTATE)/256), blk, 0, stream>>>(Ssc, Psc, Hsc);
  scan_p3<<<dim3(BSZ*128*NCHUNK), blk, 0, stream>>>(
      delta16, u, Z, xdbl, A_log, Dp, Hsc, XC);

  // GEMM4 (MFMA): out = y @ out_proj_w (2048 x 1024 x 2048)
  gemm_mfma_k<64><<<dim3(DIMX/64, NROW/128), blk, 0, stream>>>(
      XC, DINNER, w4t, DINNER, out, out, 1<<30, DIMX, DINNER);
}

// Round 7
// 291.276 us; speedup vs baseline: 3.1270x; 1.1198x over previous
//
#include <hip/hip_runtime.h>
#include <hip/hip_bf16.h>

#define DIMX 1024
#define DSTATE 16
#define DCONV 4
#define DINNER 2048
#define DTRANK 64
#define BSZ 2
#define SEQL 1024
#define NROW (BSZ*SEQL)              // 2048
#define NPROJ (DTRANK + 2*DSTATE)    // 96
#define NCHUNK 16
#define CLEN 64                      // SEQL / NCHUNK
#define G2SPLIT 16                   // GEMM2 split-K factor
#define G2KLEN (DINNER / G2SPLIT)    // 128
#define G4SPLIT 4                    // GEMM4 split-K factor
#define LSTR 68                      // scan LDS row stride (floats)

typedef __bf16 bf16x8 __attribute__((ext_vector_type(8)));
typedef float f32x4 __attribute__((ext_vector_type(4)));
typedef unsigned short ushort8_t __attribute__((ext_vector_type(8)));

#define LOG2E 1.44269504088896340736f

__device__ __forceinline__ float sigmoidf_(float x){ return 1.0f/(1.0f+__expf(-x)); }
__device__ __forceinline__ unsigned short f2bf(float f){
  union { float f; unsigned int i; } c; c.f = f;
  unsigned int r = (c.i + 0x7FFFu + ((c.i >> 16) & 1u)) >> 16;
  return (unsigned short)r;
}
__device__ __forceinline__ float bf2f(unsigned short u){
  union { unsigned int i; float f; } c; c.i = ((unsigned int)u) << 16; return c.f;
}

// async global->LDS, 16 B per lane; LDS dest = base + lane*16 (wave-uniform base)
__device__ __forceinline__ void gload16(const void* g, void* l){
  __builtin_amdgcn_global_load_lds(
      (const __attribute__((address_space(1))) unsigned int*)g,
      (__attribute__((address_space(3))) unsigned int*)l, 16, 0, 0);
}

template<int CTRL>
__device__ __forceinline__ float dpp_add(float p){
  int v = __builtin_amdgcn_update_dpp(0, __float_as_int(p), CTRL, 0xf, 0xf, true);
  return p + __int_as_float(v);
}
__device__ __forceinline__ float row_sum16(float p){
  p = dpp_add<0x111>(p);
  p = dpp_add<0x112>(p);
  p = dpp_add<0x114>(p);
  p = dpp_add<0x118>(p);   // lane n==15 holds row sum
  return p;
}

// ---------------------------------------------------------------------------
// Transpose + cast: w (K x N, f32) -> wt (N x K, bf16). Grid (N/32, K/32).
// ---------------------------------------------------------------------------
__global__ __launch_bounds__(256) void transpose_cast_k(
    const float* __restrict__ w, unsigned short* __restrict__ wt, int K, int N)
{
  __shared__ unsigned short T[32][33];
  const int nT = blockIdx.x * 32, kT = blockIdx.y * 32;
  const int tx = threadIdx.x & 31, ty = threadIdx.x >> 5;
  #pragma unroll
  for (int i = 0; i < 4; i++) {
    const int k = kT + ty + i*8;
    T[tx][ty + i*8] = f2bf(w[(size_t)k * N + nT + tx]);
  }
  __syncthreads();
  #pragma unroll
  for (int i = 0; i < 4; i++) {
    const int n = nT + ty + i*8;
    wt[(size_t)n * K + kT + tx] = T[ty + i*8][tx];
  }
}

// ---------------------------------------------------------------------------
// Cast f32 -> bf16, vectorized (n4 float4 groups).
// ---------------------------------------------------------------------------
__global__ __launch_bounds__(256) void cast_bf16_k(
    const float* __restrict__ in, unsigned short* __restrict__ outp, int n4)
{
  const int i = blockIdx.x * 256 + threadIdx.x;
  if (i >= n4) return;
  float4 v = *(const float4*)(in + (size_t)i * 4);
  ushort4 o;
  o.x = f2bf(v.x); o.y = f2bf(v.y); o.z = f2bf(v.z); o.w = f2bf(v.w);
  *(ushort4*)(outp + (size_t)i * 4) = o;
}

// ---------------------------------------------------------------------------
// m97-style bf16 MFMA GEMM: C(f32) = A(MxK bf16) @ BT^T (BT: NxK bf16).
// 128x128 tile, BK=32, 256 thr = 2x2 waves, 4x4 16x16x32 accs/wave.
// LDS unpadded stride-32 rows (required by global_load_lds lane mapping).
// KCH>0: split-K via blockIdx.z (K range [z*KCH,(z+1)*KCH), partial slice
// offset z*M*ldc). C-write splits at col splitN -> C0 / C1.
// ---------------------------------------------------------------------------
template<int KCH>
__global__ __launch_bounds__(256) void gemm_bt_k(
    const unsigned short* __restrict__ A, int lda,
    const unsigned short* __restrict__ BT, int ldb,
    float* __restrict__ C0, float* __restrict__ C1, int splitN, int ldc,
    int M, int K)
{
  constexpr int BM = 128, BN = 128, BK = 32;
  __shared__ unsigned short As[BM*BK];
  __shared__ unsigned short Bs[BN*BK];

  const int tid = threadIdx.x;
  const int w = tid >> 6, lane = tid & 63;
  const int quad = lane >> 4, lrow = lane & 15;
  const int mOff = (w & 1) * 64, nOff = (w >> 1) * 64;
  const int rowTile = blockIdx.y * BM, colTile = blockIdx.x * BN;

  int kBeg = 0, kEnd = K;
  float* c0 = C0; float* c1 = C1;
  if constexpr (KCH > 0) {
    kBeg = blockIdx.z * KCH;
    kEnd = kBeg + KCH;
    c0 += (size_t)blockIdx.z * M * ldc;
    c1 += (size_t)blockIdx.z * M * ldc;
  }

  f32x4 acc[4][4] = {};

  // staging: wave w covers rows [w*32, w*32+32), two issues of 16 rows each;
  // lane l -> row +(l>>2), byte (l&3)*16 within the 64-B LDS row.
  const int srow = lane >> 2;
  const int sbyte = (lane & 3) * 16;
  unsigned short* aB0 = &As[(w*32     )*32];
  unsigned short* aB1 = &As[(w*32 + 16)*32];
  unsigned short* bB0 = &Bs[(w*32     )*32];
  unsigned short* bB1 = &Bs[(w*32 + 16)*32];

  for (int k0 = kBeg; k0 < kEnd; k0 += BK) {
    const char* aSrc = (const char*)(A  + (size_t)(rowTile + w*32 + srow)*lda + k0) + sbyte;
    const char* bSrc = (const char*)(BT + (size_t)(colTile + w*32 + srow)*ldb + k0) + sbyte;
    gload16(aSrc,                    aB0);
    gload16(aSrc + 16*(size_t)lda*2, aB1);
    gload16(bSrc,                    bB0);
    gload16(bSrc + 16*(size_t)ldb*2, bB1);
    __syncthreads();

    bf16x8 af[4], bfr[4];
    #pragma unroll
    for (int mi = 0; mi < 4; mi++)
      af[mi] = *(const bf16x8*)&As[(mOff + mi*16 + lrow)*32 + quad*8];
    #pragma unroll
    for (int ni = 0; ni < 4; ni++)
      bfr[ni] = *(const bf16x8*)&Bs[(nOff + ni*16 + lrow)*32 + quad*8];
    #pragma unroll
    for (int mi = 0; mi < 4; mi++)
      #pragma unroll
      for (int ni = 0; ni < 4; ni++)
        acc[mi][ni] = __builtin_amdgcn_mfma_f32_16x16x32_bf16(
            af[mi], bfr[ni], acc[mi][ni], 0, 0, 0);
    __syncthreads();
  }

  #pragma unroll
  for (int mi = 0; mi < 4; mi++) {
    #pragma unroll
    for (int ni = 0; ni < 4; ni++) {
      const int row = rowTile + mOff + mi*16 + quad*4;
      const int col = colTile + nOff + ni*16 + lrow;
      float* Cb = (col < splitN) ? c0 : c1;
      const int cc = (col < splitN) ? col : col - splitN;
      #pragma unroll
      for (int r = 0; r < 4; r++)
        Cb[(size_t)(row + r) * ldc + cc] = acc[mi][ni][r];
    }
  }
}

// ---------------------------------------------------------------------------
// Tiled f32 GEMM (GEMM2 split-K, GEMM3). See R4.
// ---------------------------------------------------------------------------
template<int EPI, int OUT_BF16, int KCHUNK>
__global__ __launch_bounds__(256) void gemm_k(
    const float* __restrict__ Ap, int lda,
    const float* __restrict__ Bp, int ldb,
    void* __restrict__ Cp, int ldc,
    int M, int N, int K,
    const float* __restrict__ bias)
{
  __shared__ float As[16][64];
  __shared__ float Bs[16][64];
  const int tid = threadIdx.x;
  const int tx = tid & 15, ty = tid >> 4;
  const int rowTile = blockIdx.y * 64;
  const int colTile = blockIdx.x * 64;

  int kBeg = 0, kEnd = K;
  float* Cout = (float*)Cp;
  if constexpr (KCHUNK > 0) {
    kBeg = blockIdx.z * KCHUNK;
    kEnd = kBeg + KCHUNK;
    Cout += (size_t)blockIdx.z * M * ldc;
  }

  const int ar = tid >> 2;
  const int ak = (tid & 3) * 4;
  const int bk = tid >> 4;
  const int bn = (tid & 15) * 4;

  float acc[4][4] = {};

  for (int k0 = kBeg; k0 < kEnd; k0 += 16) {
    {
      const int r = rowTile + ar;
      float4 av = *(const float4*)(Ap + (size_t)r * lda + k0 + ak);
      As[ak+0][ar] = av.x; As[ak+1][ar] = av.y;
      As[ak+2][ar] = av.z; As[ak+3][ar] = av.w;
    }
    {
      const int kk = k0 + bk;
      const int c = colTile + bn;
      float4 bv;
      if (c + 3 < N) {
        bv = *(const float4*)(Bp + (size_t)kk * ldb + c);
      } else {
        bv.x = (c+0 < N) ? Bp[(size_t)kk*ldb + c+0] : 0.f;
        bv.y = (c+1 < N) ? Bp[(size_t)kk*ldb + c+1] : 0.f;
        bv.z = (c+2 < N) ? Bp[(size_t)kk*ldb + c+2] : 0.f;
        bv.w = (c+3 < N) ? Bp[(size_t)kk*ldb + c+3] : 0.f;
      }
      *(float4*)&Bs[bk][bn] = bv;
    }
    __syncthreads();
    #pragma unroll
    for (int kk = 0; kk < 16; kk++) {
      float4 a4 = *(const float4*)&As[kk][ty*4];
      float4 b4 = *(const float4*)&Bs[kk][tx*4];
      float a[4] = {a4.x, a4.y, a4.z, a4.w};
      float b[4] = {b4.x, b4.y, b4.z, b4.w};
      #pragma unroll
      for (int i = 0; i < 4; i++)
        #pragma unroll
        for (int j = 0; j < 4; j++)
          acc[i][j] += a[i] * b[j];
    }
    __syncthreads();
  }

  #pragma unroll
  for (int i = 0; i < 4; i++) {
    const int r = rowTile + ty*4 + i;
    #pragma unroll
    for (int j = 0; j < 4; j++) {
      const int c = colTile + tx*4 + j;
      if (c >= N) continue;
      float v = acc[i][j];
      if constexpr (EPI == 1) {
        v += bias[c];
        v = (v > 20.f) ? v : log1pf(__expf(v));
      }
      if constexpr (OUT_BF16) ((unsigned short*)Cp)[(size_t)r*ldc + c] = f2bf(v);
      else                    Cout[(size_t)r*ldc + c] = v;
    }
  }
}

// ---------------------------------------------------------------------------
// Sum NS partial C slices (each n4 float4 groups apart).
// ---------------------------------------------------------------------------
template<int NS>
__global__ __launch_bounds__(256) void reduce_split_k(
    const float* __restrict__ part, float* __restrict__ outp, int n4)
{
  const int i = blockIdx.x * 256 + threadIdx.x;
  if (i >= n4) return;
  float4 s = *(const float4*)(part + (size_t)i * 4);
  #pragma unroll
  for (int z = 1; z < NS; z++) {
    float4 v = *(const float4*)(part + (size_t)z * n4 * 4 + (size_t)i * 4);
    s.x += v.x; s.y += v.y; s.z += v.z; s.w += v.w;
  }
  *(float4*)(outp + (size_t)i * 4) = s;
}

// ---------------------------------------------------------------------------
// Causal depthwise conv (width 4) + SiLU.
// ---------------------------------------------------------------------------
__global__ __launch_bounds__(256) void conv_silu_k(
    const float* __restrict__ xc,
    const float* __restrict__ conv_w,
    const float* __restrict__ conv_b,
    float* __restrict__ u)
{
  const int idx = blockIdx.x * 256 + threadIdx.x;
  if (idx >= NROW * DINNER) return;
  const int d = idx & (DINNER - 1);
  const int row = idx >> 11;
  const int l = row & (SEQL - 1);
  float acc = conv_b[d];
  #pragma unroll
  for (int k = 0; k < DCONV; k++) {
    const int ls = l + k - (DCONV - 1);
    if (ls >= 0)
      acc += xc[(size_t)(row + k - (DCONV - 1)) * DINNER + d] * conv_w[d*DCONV + k];
  }
  u[idx] = acc * sigmoidf_(acc);
}

// ---------------------------------------------------------------------------
// Chunked parallel scan (R5-verified LDS-lean version).
// ---------------------------------------------------------------------------
__global__ __launch_bounds__(256) void scan_p1(
    const unsigned short* __restrict__ delta16,
    const float* __restrict__ u,
    const float* __restrict__ xdbl,
    const float* __restrict__ A_log,
    float* __restrict__ S, float* __restrict__ P)
{
  const int c = blockIdx.x & 15;
  const int dg = (blockIdx.x >> 4) & 127;
  const int b = blockIdx.x >> 11;
  const int dBase = dg * 16;
  const int tid = threadIdx.x;
  const int g = tid >> 4, n = tid & 15;
  const int d = dBase + g;
  const float A2 = -__expf(A_log[d*DSTATE + n]) * LOG2E;

  __shared__ float dlt_s[16][LSTR], du_s[16][LSTR], Bm_s[16][LSTR];

  const int t4 = tid >> 2, j4 = (tid & 3) * 4;
  const size_t rowL = (size_t)(b*SEQL + c*CLEN + t4);
  {
    ushort4 dv = *(const ushort4*)&delta16[rowL*DINNER + dBase + j4];
    float4  uv = *(const float4*)&u[rowL*DINNER + dBase + j4];
    float4  bv = *(const float4*)&xdbl[rowL*NPROJ + DTRANK + j4];
    const float dd[4] = {bf2f(dv.x), bf2f(dv.y), bf2f(dv.z), bf2f(dv.w)};
    const float uu[4] = {uv.x, uv.y, uv.z, uv.w};
    const float bb[4] = {bv.x, bv.y, bv.z, bv.w};
    #pragma unroll
    for (int i = 0; i < 4; i++) {
      dlt_s[j4+i][t4] = dd[i];
      du_s[j4+i][t4]  = dd[i] * uu[i];
      Bm_s[j4+i][t4]  = bb[i];
    }
  }
  __syncthreads();

  float h = 0.f, sumd = 0.f;
  for (int t0 = 0; t0 < CLEN; t0 += 4) {
    f32x4 dv  = *(const f32x4*)&dlt_s[g][t0];
    f32x4 duv = *(const f32x4*)&du_s[g][t0];
    f32x4 bv  = *(const f32x4*)&Bm_s[n][t0];
    #pragma unroll
    for (int i = 0; i < 4; i++) {
      const float a = exp2f(dv[i] * A2);
      h = a * h + duv[i] * bv[i];
      sumd += dv[i];
    }
  }
  const size_t idx = ((size_t)(b*NCHUNK + c) * DINNER + d) * DSTATE + n;
  S[idx] = h;
  P[idx] = exp2f(A2 * sumd);
}

__global__ __launch_bounds__(256) void scan_p2(
    const float* __restrict__ S, const float* __restrict__ P,
    float* __restrict__ H)
{
  const int idx = blockIdx.x * 256 + threadIdx.x;
  const int n = idx & 15, d = (idx >> 4) & (DINNER-1), b = idx >> 15;
  float h = 0.f;
  #pragma unroll
  for (int c = 0; c < NCHUNK; c++) {
    const size_t base = ((size_t)(b*NCHUNK + c) * DINNER + d) * DSTATE + n;
    H[base] = h;
    h = P[base] * h + S[base];
  }
}

__global__ __launch_bounds__(256) void scan_p3(
    const unsigned short* __restrict__ delta16,
    const float* __restrict__ u,
    const float* __restrict__ Z,
    const float* __restrict__ xdbl,
    const float* __restrict__ A_log,
    const float* __restrict__ Dp,
    const float* __restrict__ H,
    unsigned short* __restrict__ Y)        // y written as bf16 (GEMM4 A)
{
  const int c = blockIdx.x & 15;
  const int dg = (blockIdx.x >> 4) & 127;
  const int b = blockIdx.x >> 11;
  const int dBase = dg * 16;
  const int tid = threadIdx.x;
  const int g = tid >> 4, n = tid & 15;
  const int d = dBase + g;
  const float A2 = -__expf(A_log[d*DSTATE + n]) * LOG2E;

  __shared__ float dlt_s[16][LSTR], du_s[16][LSTR];
  __shared__ float Bm_s[16][LSTR], Cm_s[16][LSTR], y_s[16][LSTR];

  const int t4 = tid >> 2, j4 = (tid & 3) * 4;
  const size_t rowL = (size_t)(b*SEQL + c*CLEN + t4);
  {
    ushort4 dv = *(const ushort4*)&delta16[rowL*DINNER + dBase + j4];
    float4  uv = *(const float4*)&u[rowL*DINNER + dBase + j4];
    float4  bv = *(const float4*)&xdbl[rowL*NPROJ + DTRANK + j4];
    float4  cv = *(const float4*)&xdbl[rowL*NPROJ + DTRANK + DSTATE + j4];
    const float dd[4] = {bf2f(dv.x), bf2f(dv.y), bf2f(dv.z), bf2f(dv.w)};
    const float uu[4] = {uv.x, uv.y, uv.z, uv.w};
    const float bb[4] = {bv.x, bv.y, bv.z, bv.w};
    const float cc[4] = {cv.x, cv.y, cv.z, cv.w};
    #pragma unroll
    for (int i = 0; i < 4; i++) {
      dlt_s[j4+i][t4] = dd[i];
      du_s[j4+i][t4]  = dd[i] * uu[i];
      Bm_s[j4+i][t4]  = bb[i];
      Cm_s[j4+i][t4]  = cc[i];
    }
  }
  __syncthreads();

  float h = H[((size_t)(b*NCHUNK + c) * DINNER + d) * DSTATE + n];
  for (int t0 = 0; t0 < CLEN; t0 += 4) {
    f32x4 dv  = *(const f32x4*)&dlt_s[g][t0];
    f32x4 duv = *(const f32x4*)&du_s[g][t0];
    f32x4 bv  = *(const f32x4*)&Bm_s[n][t0];
    f32x4 cv  = *(const f32x4*)&Cm_s[n][t0];
    f32x4 yq;
    #pragma unroll
    for (int i = 0; i < 4; i++) {
      const float a = exp2f(dv[i] * A2);
      h = a * h + duv[i] * bv[i];
      yq[i] = row_sum16(h * cv[i]);
    }
    if (n == 15) *(f32x4*)&y_s[g][t0] = yq;
  }
  __syncthreads();

  {
    float4 uv = *(const float4*)&u[rowL*DINNER + dBase + j4];
    float4 zv = *(const float4*)&Z[rowL*DINNER + dBase + j4];
    float4 Dv = *(const float4*)&Dp[dBase + j4];
    const float zz[4] = {zv.x, zv.y, zv.z, zv.w};
    const float us[4] = {uv.x, uv.y, uv.z, uv.w};
    const float ds[4] = {Dv.x, Dv.y, Dv.z, Dv.w};
    ushort4 yo;
    float yy[4];
    #pragma unroll
    for (int i = 0; i < 4; i++) {
      const float p = y_s[j4+i][t4];
      yy[i] = (p + us[i]*ds[i]) * (zz[i] * sigmoidf_(zz[i]));
    }
    yo.x = f2bf(yy[0]); yo.y = f2bf(yy[1]); yo.z = f2bf(yy[2]); yo.w = f2bf(yy[3]);
    *(ushort4*)&Y[rowL*DINNER + dBase + j4] = yo;
  }
}

// ---------------------------------------------------------------------------
extern "C" void kernel_launch(void* const* d_in, const int* in_sizes, int n_in,
                              void* d_out, int out_size, void* d_ws, size_t ws_size,
                              hipStream_t stream) {
  const float* x         = (const float*)d_in[0];
  const float* in_proj_w = (const float*)d_in[2];
  const float* conv_w    = (const float*)d_in[3];
  const float* conv_b    = (const float*)d_in[4];
  const float* x_proj_w  = (const float*)d_in[5];
  const float* dt_proj_w = (const float*)d_in[6];
  const float* dt_proj_b = (const float*)d_in[7];
  const float* A_log     = (const float*)d_in[8];
  const float* Dp        = (const float*)d_in[9];
  const float* out_proj_w= (const float*)d_in[10];
  float* out = (float*)d_out;

  // ws — EXACTLY the R2-proven 67,895,296 bytes. Timeline:
  //  XC 16.78MB: xb? no -> xc f32 (GEMM1 out) -> conv reads -> g2part (12.58M)
  //             -> S|P (8M) -> yb bf16 (8.4M, scan p3 out) -> GEMM4 A
  //  Z  16.78MB: z (GEMM1 out) -> p3 reads -> GEMM4 partials slice 0-1
  //  u  16.78MB: xb bf16 (4.2M, pre-GEMM1) -> u f32 (conv out) -> GEMM4 part 2-3
  //  xdbl 0.79MB
  //  W  16.78MB: [0,8.39M) w1t / delta16; [8.39,12.58M) H; [12.58,16.78M) w4t
  float* XC   = (float*)d_ws;
  float* Z    = XC + (size_t)NROW * DINNER;
  float* u    = Z  + (size_t)NROW * DINNER;
  float* xdbl = u  + (size_t)NROW * DINNER;
  char*  W    = (char*)(xdbl + (size_t)NROW * NPROJ);
  unsigned short* w1t     = (unsigned short*)W;
  unsigned short* delta16 = (unsigned short*)W;
  float*          Hsc     = (float*)(W + 8388608);
  unsigned short* w4t     = (unsigned short*)(W + 12582912);
  unsigned short* xb      = (unsigned short*)u;     // bf16 x, dead before conv
  unsigned short* yb      = (unsigned short*)XC;    // bf16 y (p3 out, GEMM4 A)
  float* g2part = XC;
  float* Ssc = XC;
  float* Psc = XC + (size_t)BSZ * NCHUNK * DINNER * DSTATE;
  float* g4part = Z;                                // 4 x 2048x1024 f32 = Z+u

  dim3 blk(256);

  // pre-casts (independent)
  cast_bf16_k<<<dim3((NROW*DIMX/4)/256), blk, 0, stream>>>(x, xb, NROW*DIMX/4);
  transpose_cast_k<<<dim3((2*DINNER)/32, DIMX/32), blk, 0, stream>>>(
      in_proj_w, w1t, DIMX, 2*DINNER);
  transpose_cast_k<<<dim3(DIMX/32, DINNER/32), blk, 0, stream>>>(
      out_proj_w, w4t, DINNER, DIMX);

  // GEMM1 (MFMA, global_load_lds): [xc|z] = x @ in_proj_w
  gemm_bt_k<0><<<dim3((2*DINNER)/128, NROW/128), blk, 0, stream>>>(
      xb, DIMX, w1t, DIMX, XC, Z, DINNER, DINNER, NROW, DIMX);

  conv_silu_k<<<(NROW*DINNER)/256, blk, 0, stream>>>(XC, conv_w, conv_b, u);

  // GEMM2 (f32, split-K 16)
  gemm_k<0,0,G2KLEN><<<dim3((NPROJ+63)/64, NROW/64, G2SPLIT), blk, 0, stream>>>(
      u, DINNER, x_proj_w, NPROJ, g2part, NPROJ, NROW, NPROJ, DINNER, nullptr);
  reduce_split_k<G2SPLIT><<<dim3((NROW*NPROJ/4 + 255)/256), blk, 0, stream>>>(
      g2part, xdbl, NROW*NPROJ/4);

  // GEMM3 (f32, bf16 out): delta = softplus(dtr @ dt_proj_w + b)
  gemm_k<1,1,0><<<dim3(DINNER/64, NROW/64), blk, 0, stream>>>(
      xdbl, NPROJ, dt_proj_w, DINNER, delta16, DINNER, NROW, DINNER, DTRANK, dt_proj_b);

  // chunked selective scan (p3 writes y as bf16 into XC)
  scan_p1<<<dim3(BSZ*128*NCHUNK), blk, 0, stream>>>(delta16, u, xdbl, A_log, Ssc, Psc);
  scan_p2<<<dim3((BSZ*DINNER*DSTATE)/256), blk, 0, stream>>>(Ssc, Psc, Hsc);
  scan_p3<<<dim3(BSZ*128*NCHUNK), blk, 0, stream>>>(
      delta16, u, Z, xdbl, A_log, Dp, Hsc, yb);

  // GEMM4 (MFMA, split-K 4): out = y @ out_proj_w; partials in Z+u, reduce
  gemm_bt_k<DINNER/G4SPLIT><<<dim3(DIMX/128, NROW/128, G4SPLIT), blk, 0, stream>>>(
      yb, DINNER, w4t, DINNER, g4part, g4part, 1<<30, DIMX, NROW, DINNER);
  reduce_split_k<G4SPLIT><<<dim3((NROW*DIMX/4 + 255)/256), blk, 0, stream>>>(
      g4part, out, NROW*DIMX/4);
}

// Round 8
// 280.489 us; speedup vs baseline: 3.2472x; 1.0385x over previous
//
#include <hip/hip_runtime.h>
#include <hip/hip_bf16.h>

#define DIMX 1024
#define DSTATE 16
#define DCONV 4
#define DINNER 2048
#define DTRANK 64
#define BSZ 2
#define SEQL 1024
#define NROW (BSZ*SEQL)              // 2048
#define NPROJ (DTRANK + 2*DSTATE)    // 96
#define NCHUNK 16
#define CLEN 64                      // SEQL / NCHUNK
#define G2SPLIT 16                   // GEMM2 split-K factor
#define G2KLEN (DINNER / G2SPLIT)    // 128
#define G4SPLIT 4                    // GEMM4 split-K factor
#define LSTR 68                      // scan LDS row stride (floats)

typedef __bf16 bf16x8 __attribute__((ext_vector_type(8)));
typedef float f32x4 __attribute__((ext_vector_type(4)));
typedef unsigned short ushort8_t __attribute__((ext_vector_type(8)));

#define LOG2E 1.44269504088896340736f

__device__ __forceinline__ float sigmoidf_(float x){ return 1.0f/(1.0f+__expf(-x)); }
__device__ __forceinline__ float fexp2(float x){ return __builtin_amdgcn_exp2f(x); }
__device__ __forceinline__ unsigned short f2bf(float f){
  union { float f; unsigned int i; } c; c.f = f;
  unsigned int r = (c.i + 0x7FFFu + ((c.i >> 16) & 1u)) >> 16;
  return (unsigned short)r;
}
__device__ __forceinline__ float bf2f(unsigned short u){
  union { unsigned int i; float f; } c; c.i = ((unsigned int)u) << 16; return c.f;
}

// async global->LDS, 16 B per lane; LDS dest = base + lane*16 (wave-uniform base)
__device__ __forceinline__ void gload16(const void* g, void* l){
  __builtin_amdgcn_global_load_lds(
      (const __attribute__((address_space(1))) unsigned int*)g,
      (__attribute__((address_space(3))) unsigned int*)l, 16, 0, 0);
}

// DPP add; old = p (ignored: bound_ctrl=1 zero-fills) -> no v_mov 0 per step.
template<int CTRL>
__device__ __forceinline__ float dpp_add(float p){
  int v = __builtin_amdgcn_update_dpp(__float_as_int(p), __float_as_int(p),
                                      CTRL, 0xf, 0xf, true);
  return p + __int_as_float(v);
}
// ds_swizzle butterfly add (LDS pipe) — offloads VALU.
template<int MASK>
__device__ __forceinline__ float swz_add(float p){
  int v = __builtin_amdgcn_ds_swizzle(__float_as_int(p), MASK);
  return p + __int_as_float(v);
}
// Sum over each 16-lane row -> lane 15 of the row holds the sum.
// xor1,xor2 (swizzle) give aligned-4-group sums; row_shr4, row_shr8 (DPP)
// accumulate groups into lane 15.
__device__ __forceinline__ float row_sum16(float p){
  p = swz_add<0x041F>(p);   // xor 1
  p = swz_add<0x081F>(p);   // xor 2
  p = dpp_add<0x114>(p);    // row_shr:4
  p = dpp_add<0x118>(p);    // row_shr:8
  return p;
}

// ---------------------------------------------------------------------------
// Transpose + cast: w (K x N, f32) -> wt (N x K, bf16). Grid (N/32, K/32).
// ---------------------------------------------------------------------------
__global__ __launch_bounds__(256) void transpose_cast_k(
    const float* __restrict__ w, unsigned short* __restrict__ wt, int K, int N)
{
  __shared__ unsigned short T[32][33];
  const int nT = blockIdx.x * 32, kT = blockIdx.y * 32;
  const int tx = threadIdx.x & 31, ty = threadIdx.x >> 5;
  #pragma unroll
  for (int i = 0; i < 4; i++) {
    const int k = kT + ty + i*8;
    T[tx][ty + i*8] = f2bf(w[(size_t)k * N + nT + tx]);
  }
  __syncthreads();
  #pragma unroll
  for (int i = 0; i < 4; i++) {
    const int n = nT + ty + i*8;
    wt[(size_t)n * K + kT + tx] = T[ty + i*8][tx];
  }
}

// ---------------------------------------------------------------------------
// Cast f32 -> bf16, vectorized.
// ---------------------------------------------------------------------------
__global__ __launch_bounds__(256) void cast_bf16_k(
    const float* __restrict__ in, unsigned short* __restrict__ outp, int n4)
{
  const int i = blockIdx.x * 256 + threadIdx.x;
  if (i >= n4) return;
  float4 v = *(const float4*)(in + (size_t)i * 4);
  ushort4 o;
  o.x = f2bf(v.x); o.y = f2bf(v.y); o.z = f2bf(v.z); o.w = f2bf(v.w);
  *(ushort4*)(outp + (size_t)i * 4) = o;
}

// ---------------------------------------------------------------------------
// m97-style bf16 MFMA GEMM: C = A(MxK bf16) @ BT^T (BT: NxK bf16).
// 128x128 tile, BK=32, 256 thr = 2x2 waves, 4x4 16x16x32 accs/wave.
// KCH>0: split-K via blockIdx.z. EPI: softplus(v+bias[col]). OUTBF: bf16 out.
// ---------------------------------------------------------------------------
template<int KCH, int EPI, int OUTBF>
__global__ __launch_bounds__(256) void gemm_bt_k(
    const unsigned short* __restrict__ A, int lda,
    const unsigned short* __restrict__ BT, int ldb,
    void* __restrict__ C0v, void* __restrict__ C1v, int splitN, int ldc,
    int M, int K, const float* __restrict__ bias)
{
  constexpr int BM = 128, BN = 128, BK = 32;
  __shared__ unsigned short As[BM*BK];
  __shared__ unsigned short Bs[BN*BK];

  const int tid = threadIdx.x;
  const int w = tid >> 6, lane = tid & 63;
  const int quad = lane >> 4, lrow = lane & 15;
  const int mOff = (w & 1) * 64, nOff = (w >> 1) * 64;
  const int rowTile = blockIdx.y * BM, colTile = blockIdx.x * BN;

  int kBeg = 0, kEnd = K;
  float* c0 = (float*)C0v; float* c1 = (float*)C1v;
  if constexpr (KCH > 0) {
    kBeg = blockIdx.z * KCH;
    kEnd = kBeg + KCH;
    c0 += (size_t)blockIdx.z * M * ldc;
    c1 += (size_t)blockIdx.z * M * ldc;
  }

  f32x4 acc[4][4] = {};

  const int srow = lane >> 2;
  const int sbyte = (lane & 3) * 16;
  unsigned short* aB0 = &As[(w*32     )*32];
  unsigned short* aB1 = &As[(w*32 + 16)*32];
  unsigned short* bB0 = &Bs[(w*32     )*32];
  unsigned short* bB1 = &Bs[(w*32 + 16)*32];

  for (int k0 = kBeg; k0 < kEnd; k0 += BK) {
    const char* aSrc = (const char*)(A  + (size_t)(rowTile + w*32 + srow)*lda + k0) + sbyte;
    const char* bSrc = (const char*)(BT + (size_t)(colTile + w*32 + srow)*ldb + k0) + sbyte;
    gload16(aSrc,                    aB0);
    gload16(aSrc + 16*(size_t)lda*2, aB1);
    gload16(bSrc,                    bB0);
    gload16(bSrc + 16*(size_t)ldb*2, bB1);
    __syncthreads();

    bf16x8 af[4], bfr[4];
    #pragma unroll
    for (int mi = 0; mi < 4; mi++)
      af[mi] = *(const bf16x8*)&As[(mOff + mi*16 + lrow)*32 + quad*8];
    #pragma unroll
    for (int ni = 0; ni < 4; ni++)
      bfr[ni] = *(const bf16x8*)&Bs[(nOff + ni*16 + lrow)*32 + quad*8];
    #pragma unroll
    for (int mi = 0; mi < 4; mi++)
      #pragma unroll
      for (int ni = 0; ni < 4; ni++)
        acc[mi][ni] = __builtin_amdgcn_mfma_f32_16x16x32_bf16(
            af[mi], bfr[ni], acc[mi][ni], 0, 0, 0);
    __syncthreads();
  }

  #pragma unroll
  for (int mi = 0; mi < 4; mi++) {
    #pragma unroll
    for (int ni = 0; ni < 4; ni++) {
      const int row = rowTile + mOff + mi*16 + quad*4;
      const int col = colTile + nOff + ni*16 + lrow;
      float* Cb = (col < splitN) ? c0 : c1;
      const int cc = (col < splitN) ? col : col - splitN;
      #pragma unroll
      for (int r = 0; r < 4; r++) {
        float v = acc[mi][ni][r];
        if constexpr (EPI) {
          v += bias[col];
          v = (v > 20.f) ? v : log1pf(__expf(v));
        }
        if constexpr (OUTBF)
          ((unsigned short*)C0v)[(size_t)(row + r) * ldc + cc] = f2bf(v);
        else
          Cb[(size_t)(row + r) * ldc + cc] = v;
      }
    }
  }
}

// ---------------------------------------------------------------------------
// Tiled f32 GEMM (GEMM2 split-K only now).
// ---------------------------------------------------------------------------
template<int KCHUNK>
__global__ __launch_bounds__(256) void gemm_k(
    const float* __restrict__ Ap, int lda,
    const float* __restrict__ Bp, int ldb,
    float* __restrict__ Cp, int ldc,
    int M, int N, int K)
{
  __shared__ float As[16][64];
  __shared__ float Bs[16][64];
  const int tid = threadIdx.x;
  const int tx = tid & 15, ty = tid >> 4;
  const int rowTile = blockIdx.y * 64;
  const int colTile = blockIdx.x * 64;

  int kBeg = 0, kEnd = K;
  float* Cout = Cp;
  if constexpr (KCHUNK > 0) {
    kBeg = blockIdx.z * KCHUNK;
    kEnd = kBeg + KCHUNK;
    Cout += (size_t)blockIdx.z * M * ldc;
  }

  const int ar = tid >> 2;
  const int ak = (tid & 3) * 4;
  const int bk = tid >> 4;
  const int bn = (tid & 15) * 4;

  float acc[4][4] = {};

  for (int k0 = kBeg; k0 < kEnd; k0 += 16) {
    {
      const int r = rowTile + ar;
      float4 av = *(const float4*)(Ap + (size_t)r * lda + k0 + ak);
      As[ak+0][ar] = av.x; As[ak+1][ar] = av.y;
      As[ak+2][ar] = av.z; As[ak+3][ar] = av.w;
    }
    {
      const int kk = k0 + bk;
      const int c = colTile + bn;
      float4 bv;
      if (c + 3 < N) {
        bv = *(const float4*)(Bp + (size_t)kk * ldb + c);
      } else {
        bv.x = (c+0 < N) ? Bp[(size_t)kk*ldb + c+0] : 0.f;
        bv.y = (c+1 < N) ? Bp[(size_t)kk*ldb + c+1] : 0.f;
        bv.z = (c+2 < N) ? Bp[(size_t)kk*ldb + c+2] : 0.f;
        bv.w = (c+3 < N) ? Bp[(size_t)kk*ldb + c+3] : 0.f;
      }
      *(float4*)&Bs[bk][bn] = bv;
    }
    __syncthreads();
    #pragma unroll
    for (int kk = 0; kk < 16; kk++) {
      float4 a4 = *(const float4*)&As[kk][ty*4];
      float4 b4 = *(const float4*)&Bs[kk][tx*4];
      float a[4] = {a4.x, a4.y, a4.z, a4.w};
      float b[4] = {b4.x, b4.y, b4.z, b4.w};
      #pragma unroll
      for (int i = 0; i < 4; i++)
        #pragma unroll
        for (int j = 0; j < 4; j++)
          acc[i][j] += a[i] * b[j];
    }
    __syncthreads();
  }

  #pragma unroll
  for (int i = 0; i < 4; i++) {
    const int r = rowTile + ty*4 + i;
    #pragma unroll
    for (int j = 0; j < 4; j++) {
      const int c = colTile + tx*4 + j;
      if (c >= N) continue;
      Cout[(size_t)r*ldc + c] = acc[i][j];
    }
  }
}

// ---------------------------------------------------------------------------
// GEMM2 reduce: sum 16 partial slices -> xdbl f32; also emit dtr cols as bf16.
// ---------------------------------------------------------------------------
__global__ __launch_bounds__(256) void reduce_g2_k(
    const float* __restrict__ part, float* __restrict__ outp,
    unsigned short* __restrict__ dtr16)
{
  const int n4 = NROW*NPROJ/4;
  const int i = blockIdx.x * 256 + threadIdx.x;
  if (i >= n4) return;
  float4 s = *(const float4*)(part + (size_t)i * 4);
  #pragma unroll
  for (int z = 1; z < G2SPLIT; z++) {
    float4 v = *(const float4*)(part + (size_t)z * n4 * 4 + (size_t)i * 4);
    s.x += v.x; s.y += v.y; s.z += v.z; s.w += v.w;
  }
  *(float4*)(outp + (size_t)i * 4) = s;
  const int col = (i*4) % NPROJ, row = (i*4) / NPROJ;
  if (col < DTRANK) {
    ushort4 o;
    o.x = f2bf(s.x); o.y = f2bf(s.y); o.z = f2bf(s.z); o.w = f2bf(s.w);
    *(ushort4*)(dtr16 + (size_t)row * DTRANK + col) = o;
  }
}

// ---------------------------------------------------------------------------
// GEMM4 reduce: sum 4 partial slices -> out f32.
// ---------------------------------------------------------------------------
__global__ __launch_bounds__(256) void reduce_g4_k(
    const float* __restrict__ part, float* __restrict__ outp, int n4)
{
  const int i = blockIdx.x * 256 + threadIdx.x;
  if (i >= n4) return;
  float4 s = *(const float4*)(part + (size_t)i * 4);
  #pragma unroll
  for (int z = 1; z < G4SPLIT; z++) {
    float4 v = *(const float4*)(part + (size_t)z * n4 * 4 + (size_t)i * 4);
    s.x += v.x; s.y += v.y; s.z += v.z; s.w += v.w;
  }
  *(float4*)(outp + (size_t)i * 4) = s;
}

// ---------------------------------------------------------------------------
// Causal depthwise conv (width 4) + SiLU.
// ---------------------------------------------------------------------------
__global__ __launch_bounds__(256) void conv_silu_k(
    const float* __restrict__ xc,
    const float* __restrict__ conv_w,
    const float* __restrict__ conv_b,
    float* __restrict__ u)
{
  const int idx = blockIdx.x * 256 + threadIdx.x;
  if (idx >= NROW * DINNER) return;
  const int d = idx & (DINNER - 1);
  const int row = idx >> 11;
  const int l = row & (SEQL - 1);
  float acc = conv_b[d];
  #pragma unroll
  for (int k = 0; k < DCONV; k++) {
    const int ls = l + k - (DCONV - 1);
    if (ls >= 0)
      acc += xc[(size_t)(row + k - (DCONV - 1)) * DINNER + d] * conv_w[d*DCONV + k];
  }
  u[idx] = acc * sigmoidf_(acc);
}

// ---------------------------------------------------------------------------
// Chunked parallel scan.
// ---------------------------------------------------------------------------
__global__ __launch_bounds__(256) void scan_p1(
    const unsigned short* __restrict__ delta16,
    const float* __restrict__ u,
    const float* __restrict__ xdbl,
    const float* __restrict__ A_log,
    float* __restrict__ S, float* __restrict__ P)
{
  const int c = blockIdx.x & 15;
  const int dg = (blockIdx.x >> 4) & 127;
  const int b = blockIdx.x >> 11;
  const int dBase = dg * 16;
  const int tid = threadIdx.x;
  const int g = tid >> 4, n = tid & 15;
  const int d = dBase + g;
  const float A2 = -__expf(A_log[d*DSTATE + n]) * LOG2E;

  __shared__ float dlt_s[16][LSTR], du_s[16][LSTR], Bm_s[16][LSTR];

  const int t4 = tid >> 2, j4 = (tid & 3) * 4;
  const size_t rowL = (size_t)(b*SEQL + c*CLEN + t4);
  {
    ushort4 dv = *(const ushort4*)&delta16[rowL*DINNER + dBase + j4];
    float4  uv = *(const float4*)&u[rowL*DINNER + dBase + j4];
    float4  bv = *(const float4*)&xdbl[rowL*NPROJ + DTRANK + j4];
    const float dd[4] = {bf2f(dv.x), bf2f(dv.y), bf2f(dv.z), bf2f(dv.w)};
    const float uu[4] = {uv.x, uv.y, uv.z, uv.w};
    const float bb[4] = {bv.x, bv.y, bv.z, bv.w};
    #pragma unroll
    for (int i = 0; i < 4; i++) {
      dlt_s[j4+i][t4] = dd[i];
      du_s[j4+i][t4]  = dd[i] * uu[i];
      Bm_s[j4+i][t4]  = bb[i];
    }
  }
  __syncthreads();

  float h = 0.f, sumd = 0.f;
  for (int t0 = 0; t0 < CLEN; t0 += 4) {
    f32x4 dv  = *(const f32x4*)&dlt_s[g][t0];
    f32x4 duv = *(const f32x4*)&du_s[g][t0];
    f32x4 bv  = *(const f32x4*)&Bm_s[n][t0];
    #pragma unroll
    for (int i = 0; i < 4; i++) {
      const float a = fexp2(dv[i] * A2);
      h = a * h + duv[i] * bv[i];
      sumd += dv[i];
    }
  }
  const size_t idx = ((size_t)(b*NCHUNK + c) * DINNER + d) * DSTATE + n;
  S[idx] = h;
  P[idx] = fexp2(A2 * sumd);
}

__global__ __launch_bounds__(256) void scan_p2(
    const float* __restrict__ S, const float* __restrict__ P,
    float* __restrict__ H)
{
  const int idx = blockIdx.x * 256 + threadIdx.x;
  const int n = idx & 15, d = (idx >> 4) & (DINNER-1), b = idx >> 15;
  float h = 0.f;
  #pragma unroll
  for (int c = 0; c < NCHUNK; c++) {
    const size_t base = ((size_t)(b*NCHUNK + c) * DINNER + d) * DSTATE + n;
    H[base] = h;
    h = P[base] * h + S[base];
  }
}

__global__ __launch_bounds__(256) void scan_p3(
    const unsigned short* __restrict__ delta16,
    const float* __restrict__ u,
    const float* __restrict__ Z,
    const float* __restrict__ xdbl,
    const float* __restrict__ A_log,
    const float* __restrict__ Dp,
    const float* __restrict__ H,
    unsigned short* __restrict__ Y)        // y written as bf16 (GEMM4 A)
{
  const int c = blockIdx.x & 15;
  const int dg = (blockIdx.x >> 4) & 127;
  const int b = blockIdx.x >> 11;
  const int dBase = dg * 16;
  const int tid = threadIdx.x;
  const int g = tid >> 4, n = tid & 15;
  const int d = dBase + g;
  const float A2 = -__expf(A_log[d*DSTATE + n]) * LOG2E;

  __shared__ float dlt_s[16][LSTR], du_s[16][LSTR];
  __shared__ float Bm_s[16][LSTR], Cm_s[16][LSTR], y_s[16][LSTR];

  const int t4 = tid >> 2, j4 = (tid & 3) * 4;
  const size_t rowL = (size_t)(b*SEQL + c*CLEN + t4);
  {
    ushort4 dv = *(const ushort4*)&delta16[rowL*DINNER + dBase + j4];
    float4  uv = *(const float4*)&u[rowL*DINNER + dBase + j4];
    float4  bv = *(const float4*)&xdbl[rowL*NPROJ + DTRANK + j4];
    float4  cv = *(const float4*)&xdbl[rowL*NPROJ + DTRANK + DSTATE + j4];
    const float dd[4] = {bf2f(dv.x), bf2f(dv.y), bf2f(dv.z), bf2f(dv.w)};
    const float uu[4] = {uv.x, uv.y, uv.z, uv.w};
    const float bb[4] = {bv.x, bv.y, bv.z, bv.w};
    const float cc[4] = {cv.x, cv.y, cv.z, cv.w};
    #pragma unroll
    for (int i = 0; i < 4; i++) {
      dlt_s[j4+i][t4] = dd[i];
      du_s[j4+i][t4]  = dd[i] * uu[i];
      Bm_s[j4+i][t4]  = bb[i];
      Cm_s[j4+i][t4]  = cc[i];
    }
  }
  __syncthreads();

  float h = H[((size_t)(b*NCHUNK + c) * DINNER + d) * DSTATE + n];
  for (int t0 = 0; t0 < CLEN; t0 += 4) {
    f32x4 dv  = *(const f32x4*)&dlt_s[g][t0];
    f32x4 duv = *(const f32x4*)&du_s[g][t0];
    f32x4 bv  = *(const f32x4*)&Bm_s[n][t0];
    f32x4 cv  = *(const f32x4*)&Cm_s[n][t0];
    f32x4 yq;
    #pragma unroll
    for (int i = 0; i < 4; i++) {
      const float a = fexp2(dv[i] * A2);
      h = a * h + duv[i] * bv[i];
      yq[i] = row_sum16(h * cv[i]);
    }
    if (n == 15) *(f32x4*)&y_s[g][t0] = yq;
  }
  __syncthreads();

  {
    float4 uv = *(const float4*)&u[rowL*DINNER + dBase + j4];
    float4 zv = *(const float4*)&Z[rowL*DINNER + dBase + j4];
    float4 Dv = *(const float4*)&Dp[dBase + j4];
    const float zz[4] = {zv.x, zv.y, zv.z, zv.w};
    const float us[4] = {uv.x, uv.y, uv.z, uv.w};
    const float ds[4] = {Dv.x, Dv.y, Dv.z, Dv.w};
    ushort4 yo;
    float yy[4];
    #pragma unroll
    for (int i = 0; i < 4; i++) {
      const float p = y_s[j4+i][t4];
      yy[i] = (p + us[i]*ds[i]) * (zz[i] * sigmoidf_(zz[i]));
    }
    yo.x = f2bf(yy[0]); yo.y = f2bf(yy[1]); yo.z = f2bf(yy[2]); yo.w = f2bf(yy[3]);
    *(ushort4*)&Y[rowL*DINNER + dBase + j4] = yo;
  }
}

// ---------------------------------------------------------------------------
extern "C" void kernel_launch(void* const* d_in, const int* in_sizes, int n_in,
                              void* d_out, int out_size, void* d_ws, size_t ws_size,
                              hipStream_t stream) {
  const float* x         = (const float*)d_in[0];
  const float* in_proj_w = (const float*)d_in[2];
  const float* conv_w    = (const float*)d_in[3];
  const float* conv_b    = (const float*)d_in[4];
  const float* x_proj_w  = (const float*)d_in[5];
  const float* dt_proj_w = (const float*)d_in[6];
  const float* dt_proj_b = (const float*)d_in[7];
  const float* A_log     = (const float*)d_in[8];
  const float* Dp        = (const float*)d_in[9];
  const float* out_proj_w= (const float*)d_in[10];
  float* out = (float*)d_out;

  // ws — EXACTLY the R2-proven 67,895,296 bytes. Timeline:
  //  XC 16.78MB: xc f32 (GEMM1) -> conv reads -> g2part[0,12.58M) +
  //     dtw_t/dtr16 in tail [12.58M,13.11M) -> S|P [0,8.39M) -> yb bf16 -> GEMM4 A
  //  Z  16.78MB: z (GEMM1) -> p3 reads -> GEMM4 partials 0-1
  //  u  16.78MB: xb bf16 (pre-GEMM1) -> u f32 (conv) -> GEMM4 partials 2-3
  //  xdbl 0.79MB
  //  W  16.78MB: [0,8.39M) w1t / delta16; [8.39,12.58M) H; [12.58,16.78M) w4t
  float* XC   = (float*)d_ws;
  float* Z    = XC + (size_t)NROW * DINNER;
  float* u    = Z  + (size_t)NROW * DINNER;
  float* xdbl = u  + (size_t)NROW * DINNER;
  char*  W    = (char*)(xdbl + (size_t)NROW * NPROJ);
  unsigned short* w1t     = (unsigned short*)W;
  unsigned short* delta16 = (unsigned short*)W;
  float*          Hsc     = (float*)(W + 8388608);
  unsigned short* w4t     = (unsigned short*)(W + 12582912);
  unsigned short* xb      = (unsigned short*)u;     // bf16 x, dead before conv
  unsigned short* yb      = (unsigned short*)XC;    // bf16 y (p3 out, GEMM4 A)
  float* g2part = XC;                               // [0, 12.58M)
  unsigned short* dtwt  = (unsigned short*)((char*)XC + 12582912);  // 256KB
  unsigned short* dtr16 = (unsigned short*)((char*)XC + 12582912 + 262144);
  float* Ssc = XC;
  float* Psc = XC + (size_t)BSZ * NCHUNK * DINNER * DSTATE;
  float* g4part = Z;                                // 4 slices across Z+u

  dim3 blk(256);

  // pre-casts (independent of data path except x)
  cast_bf16_k<<<dim3((NROW*DIMX/4)/256), blk, 0, stream>>>(x, xb, NROW*DIMX/4);
  transpose_cast_k<<<dim3((2*DINNER)/32, DIMX/32), blk, 0, stream>>>(
      in_proj_w, w1t, DIMX, 2*DINNER);
  transpose_cast_k<<<dim3(DIMX/32, DINNER/32), blk, 0, stream>>>(
      out_proj_w, w4t, DINNER, DIMX);

  // GEMM1 (MFMA): [xc|z] = x @ in_proj_w
  gemm_bt_k<0,0,0><<<dim3((2*DINNER)/128, NROW/128), blk, 0, stream>>>(
      xb, DIMX, w1t, DIMX, XC, Z, DINNER, DINNER, NROW, DIMX, nullptr);

  conv_silu_k<<<(NROW*DINNER)/256, blk, 0, stream>>>(XC, conv_w, conv_b, u);

  // dt_proj_w transpose (XC tail free after conv)
  transpose_cast_k<<<dim3(DINNER/32, DTRANK/32), blk, 0, stream>>>(
      dt_proj_w, dtwt, DTRANK, DINNER);

  // GEMM2 (f32, split-K 16) -> xdbl (+ dtr16 bf16 in reduce)
  gemm_k<G2KLEN><<<dim3((NPROJ+63)/64, NROW/64, G2SPLIT), blk, 0, stream>>>(
      u, DINNER, x_proj_w, NPROJ, g2part, NPROJ, NROW, NPROJ, DINNER);
  reduce_g2_k<<<dim3((NROW*NPROJ/4 + 255)/256), blk, 0, stream>>>(
      g2part, xdbl, dtr16);

  // GEMM3 (MFMA, K=64): delta16 = softplus(dtr16 @ dtwt^T + dt_proj_b), bf16
  gemm_bt_k<0,1,1><<<dim3(DINNER/128, NROW/128), blk, 0, stream>>>(
      dtr16, DTRANK, dtwt, DTRANK, delta16, delta16, 1<<30, DINNER,
      NROW, DTRANK, dt_proj_b);

  // chunked selective scan
  scan_p1<<<dim3(BSZ*128*NCHUNK), blk, 0, stream>>>(delta16, u, xdbl, A_log, Ssc, Psc);
  scan_p2<<<dim3((BSZ*DINNER*DSTATE)/256), blk, 0, stream>>>(Ssc, Psc, Hsc);
  scan_p3<<<dim3(BSZ*128*NCHUNK), blk, 0, stream>>>(
      delta16, u, Z, xdbl, A_log, Dp, Hsc, yb);

  // GEMM4 (MFMA, split-K 4): out = y @ out_proj_w
  gemm_bt_k<DINNER/G4SPLIT,0,0><<<dim3(DIMX/128, NROW/128, G4SPLIT), blk, 0, stream>>>(
      yb, DINNER, w4t, DINNER, g4part, g4part, 1<<30, DIMX, NROW, DINNER, nullptr);
  reduce_g4_k<<<dim3((NROW*DIMX/4 + 255)/256), blk, 0, stream>>>(
      g4part, out, NROW*DIMX/4);
}